// Round 1
// baseline (4815.572 us; speedup 1.0000x reference)
//
#include <hip/hip_runtime.h>

// Problem constants
constexpr int kN   = 40000;
constexpr int kHID = 128;
constexpr int kNH  = 8;
constexpr int kHD  = 16;       // head dim
constexpr int kE   = 640000;
constexpr int kBG  = 64;
constexpr int kItems = kE * kNH;   // 5,120,000 (edge, head) pairs

// ws layout (in floats)
constexpr size_t OFF_Q  = 0;                       // N*HID
constexpr size_t OFF_K  = (size_t)kN * kHID;       // N*HID
constexpr size_t OFF_V  = OFF_K + (size_t)kN * kHID;
constexpr size_t OFF_P  = OFF_V + (size_t)kN * kHID;   // E*NH
constexpr size_t OFF_FE = OFF_P + (size_t)kE * kNH;    // BG*HID
constexpr size_t OFF_Z  = OFF_FE + (size_t)kBG * kHID; // 8
// agg aliases Q (Q is dead after k_scores)
constexpr size_t OFF_AGG = OFF_Q;

// ---------------- field embedding: FE[g][c] = fv[g]@Wf + bf ----------------
__global__ void k_fe(const float* __restrict__ fv, const float* __restrict__ Wf,
                     const float* __restrict__ bf, float* __restrict__ FE) {
    int g = blockIdx.x;     // 64
    int c = threadIdx.x;    // 128
    float acc = bf[c]
              + fv[g * 3 + 0] * Wf[0 * kHID + c]
              + fv[g * 3 + 1] * Wf[1 * kHID + c]
              + fv[g * 3 + 2] * Wf[2 * kHID + c];
    FE[g * kHID + c] = acc;
}

// ---------------- QKV projections (+ FE added to K) ----------------
__global__ __launch_bounds__(256) void k_qkv(
    const float* __restrict__ x, const int* __restrict__ batch,
    const float* __restrict__ Wq, const float* __restrict__ bq,
    const float* __restrict__ Wk, const float* __restrict__ bk,
    const float* __restrict__ Wv, const float* __restrict__ bv,
    const float* __restrict__ FE,
    float* __restrict__ Q, float* __restrict__ Kp, float* __restrict__ V)
{
    __shared__ __align__(16) float xs[16][kHID];
    int row0 = blockIdx.x * 16;
    int tid  = threadIdx.x;

    for (int idx = tid; idx < 16 * 32; idx += 256) {
        int r = idx >> 5, c4 = idx & 31;
        int node = row0 + r;
        float4 v = (node < kN) ? ((const float4*)x)[(size_t)node * 32 + c4]
                               : make_float4(0.f, 0.f, 0.f, 0.f);
        ((float4*)&xs[r][0])[c4] = v;
    }
    __syncthreads();

    int c  = tid & 127;
    int rg = tid >> 7;     // 0 or 1
    float aq[8], ak[8], av[8];
    float bqc = bq[c], bkc = bk[c], bvc = bv[c];
#pragma unroll
    for (int m = 0; m < 8; m++) { aq[m] = bqc; ak[m] = bkc; av[m] = bvc; }

#pragma unroll 4
    for (int k = 0; k < kHID; k++) {
        float wq = Wq[k * kHID + c];
        float wk = Wk[k * kHID + c];
        float wv = Wv[k * kHID + c];
#pragma unroll
        for (int m = 0; m < 8; m++) {
            float xv = xs[m * 2 + rg][k];   // LDS broadcast (uniform addr per wave)
            aq[m] = fmaf(xv, wq, aq[m]);
            ak[m] = fmaf(xv, wk, ak[m]);
            av[m] = fmaf(xv, wv, av[m]);
        }
    }
#pragma unroll
    for (int m = 0; m < 8; m++) {
        int node = row0 + m * 2 + rg;
        if (node < kN) {
            int b = batch[node];
            Q[(size_t)node * kHID + c]  = aq[m];
            Kp[(size_t)node * kHID + c] = ak[m] + FE[b * kHID + c];
            V[(size_t)node * kHID + c]  = av[m];
        }
    }
}

// ---------------- edge scores -> P = exp(QK/4), Z[h] = sum_e P ----------------
__global__ __launch_bounds__(256) void k_scores(
    const int* __restrict__ ei, const float* __restrict__ Q,
    const float* __restrict__ Kp, float* __restrict__ P, float* __restrict__ Z)
{
    int tid = threadIdx.x;
    int h = tid & 7;              // fixed per thread (stride multiple of 8)
    float zsum = 0.f;
    const float4* Q4 = (const float4*)Q;
    const float4* K4 = (const float4*)Kp;
    int stride = gridDim.x * blockDim.x;
    for (int g = blockIdx.x * blockDim.x + tid; g < kItems; g += stride) {
        int e = g >> 3;
        int s = ei[e];
        int d = ei[kE + e];
        const float4* q = Q4 + (size_t)s * 32 + h * 4;
        const float4* k = K4 + (size_t)d * 32 + h * 4;
        float dot = 0.f;
#pragma unroll
        for (int j = 0; j < 4; j++) {
            float4 qa = q[j], ka = k[j];
            dot += qa.x * ka.x + qa.y * ka.y + qa.z * ka.z + qa.w * ka.w;
        }
        float p = __expf(dot * 0.25f);
        P[g] = p;
        zsum += p;
    }
    // reduce over lanes with same h (h = lane&7): fold lane bits 3,4,5
    zsum += __shfl_xor(zsum, 8);
    zsum += __shfl_xor(zsum, 16);
    zsum += __shfl_xor(zsum, 32);
    __shared__ float zl[8];
    if (tid < 8) zl[tid] = 0.f;
    __syncthreads();
    if ((tid & 63) < 8) atomicAdd(&zl[tid & 7], zsum);
    __syncthreads();
    if (tid < 8) atomicAdd(&Z[tid], zl[tid]);
}

// ---------------- aggregation: agg[src] += (P/Z) * V[dst] ----------------
__global__ __launch_bounds__(256) void k_agg(
    const int* __restrict__ ei, const float* __restrict__ V,
    const float* __restrict__ P, const float* __restrict__ Z,
    float* __restrict__ agg)
{
    __shared__ float invZ[8];
    int tid = threadIdx.x;
    if (tid < 8) invZ[tid] = 1.0f / Z[tid];
    __syncthreads();
    int h = tid & 7;
    float iz = invZ[h];
    const float4* V4 = (const float4*)V;
    int stride = gridDim.x * blockDim.x;
    for (int g = blockIdx.x * blockDim.x + tid; g < kItems; g += stride) {
        int e = g >> 3;
        int s = ei[e];
        int d = ei[kE + e];
        float w = P[g] * iz;
        float* dstp = agg + (size_t)s * kHID + h * kHD;
        const float4* v = V4 + (size_t)d * 32 + h * 4;
#pragma unroll
        for (int j = 0; j < 4; j++) {
            float4 va = v[j];
            atomicAdd(dstp + j * 4 + 0, w * va.x);
            atomicAdd(dstp + j * 4 + 1, w * va.y);
            atomicAdd(dstp + j * 4 + 2, w * va.z);
            atomicAdd(dstp + j * 4 + 3, w * va.w);
        }
    }
}

// ---------------- output: out = x + agg @ Wo + bo ----------------
__global__ __launch_bounds__(256) void k_out(
    const float* __restrict__ agg, const float* __restrict__ Wo,
    const float* __restrict__ bo, const float* __restrict__ x,
    float* __restrict__ out)
{
    __shared__ __align__(16) float as_[16][kHID];
    int row0 = blockIdx.x * 16;
    int tid = threadIdx.x;
    for (int idx = tid; idx < 16 * 32; idx += 256) {
        int r = idx >> 5, c4 = idx & 31;
        int node = row0 + r;
        float4 v = (node < kN) ? ((const float4*)agg)[(size_t)node * 32 + c4]
                               : make_float4(0.f, 0.f, 0.f, 0.f);
        ((float4*)&as_[r][0])[c4] = v;
    }
    __syncthreads();
    int c = tid & 127, rg = tid >> 7;
    float acc[8];
    float boc = bo[c];
#pragma unroll
    for (int m = 0; m < 8; m++) acc[m] = boc;
#pragma unroll 4
    for (int k = 0; k < kHID; k++) {
        float wo = Wo[k * kHID + c];
#pragma unroll
        for (int m = 0; m < 8; m++)
            acc[m] = fmaf(as_[m * 2 + rg][k], wo, acc[m]);
    }
#pragma unroll
    for (int m = 0; m < 8; m++) {
        int node = row0 + m * 2 + rg;
        if (node < kN)
            out[(size_t)node * kHID + c] = x[(size_t)node * kHID + c] + acc[m];
    }
}

extern "C" void kernel_launch(void* const* d_in, const int* in_sizes, int n_in,
                              void* d_out, int out_size, void* d_ws, size_t ws_size,
                              hipStream_t stream) {
    const float* x     = (const float*)d_in[0];
    const int*   ei    = (const int*)d_in[1];
    // d_in[2] = edge_attr (unused by reference)
    const float* fv    = (const float*)d_in[3];
    const int*   batch = (const int*)d_in[4];
    const float* Wq = (const float*)d_in[5];  const float* bq = (const float*)d_in[6];
    const float* Wk = (const float*)d_in[7];  const float* bk = (const float*)d_in[8];
    const float* Wv = (const float*)d_in[9];  const float* bv = (const float*)d_in[10];
    const float* Wf = (const float*)d_in[11]; const float* bf = (const float*)d_in[12];
    const float* Wo = (const float*)d_in[13]; const float* bo = (const float*)d_in[14];

    float* ws  = (float*)d_ws;
    float* Q   = ws + OFF_Q;
    float* Kp  = ws + OFF_K;
    float* V   = ws + OFF_V;
    float* P   = ws + OFF_P;
    float* FE  = ws + OFF_FE;
    float* Z   = ws + OFF_Z;
    float* agg = ws + OFF_AGG;   // aliases Q (dead after k_scores)
    float* out = (float*)d_out;

    // zero Z before scores
    hipMemsetAsync(Z, 0, kNH * sizeof(float), stream);

    k_fe<<<kBG, kHID, 0, stream>>>(fv, Wf, bf, FE);

    k_qkv<<<(kN + 15) / 16, 256, 0, stream>>>(x, batch, Wq, bq, Wk, bk, Wv, bv,
                                              FE, Q, Kp, V);

    k_scores<<<1280, 256, 0, stream>>>(ei, Q, Kp, P, Z);

    // agg aliases Q; zero it only after k_scores has consumed Q (stream order)
    hipMemsetAsync(agg, 0, (size_t)kN * kHID * sizeof(float), stream);

    k_agg<<<1280, 256, 0, stream>>>(ei, V, P, Z, agg);

    k_out<<<(kN + 15) / 16, 256, 0, stream>>>(agg, Wo, bo, x, out);
}

// Round 2
// 367.556 us; speedup vs baseline: 13.1016x; 13.1016x over previous
//
#include <hip/hip_runtime.h>

// Problem constants
constexpr int kN   = 40000;
constexpr int kHID = 128;
constexpr int kNH  = 8;
constexpr int kE   = 640000;
constexpr int kBG  = 64;
constexpr int kItems = kE * kNH;   // 5,120,000 (edge, head) pairs

// ws layout (in float/int units, 4B each)
constexpr size_t OFF_Q      = 0;                            // N*HID
constexpr size_t OFF_K      = (size_t)kN * kHID;
constexpr size_t OFF_V      = OFF_K + (size_t)kN * kHID;
constexpr size_t OFF_P      = OFF_V + (size_t)kN * kHID;    // E*NH
constexpr size_t OFF_FE     = OFF_P + (size_t)kE * kNH;     // BG*HID
constexpr size_t OFF_Z      = OFF_FE + (size_t)kBG * kHID;  // 8
constexpr size_t OFF_CNT    = OFF_Z + 8;                    // N ints
constexpr size_t OFF_ROWPTR = OFF_CNT + kN;                 // N+1 ints
constexpr size_t OFF_CURSOR = OFF_ROWPTR + kN + 1;          // N ints
constexpr size_t OFF_EID    = OFF_CURSOR + kN;              // E ints
// agg aliases Q (Q dead after k_scores)
constexpr size_t OFF_AGG    = OFF_Q;

// ---------------- field embedding ----------------
__global__ void k_fe(const float* __restrict__ fv, const float* __restrict__ Wf,
                     const float* __restrict__ bf, float* __restrict__ FE) {
    int g = blockIdx.x;     // 64
    int c = threadIdx.x;    // 128
    float acc = bf[c]
              + fv[g * 3 + 0] * Wf[0 * kHID + c]
              + fv[g * 3 + 1] * Wf[1 * kHID + c]
              + fv[g * 3 + 2] * Wf[2 * kHID + c];
    FE[g * kHID + c] = acc;
}

// ---------------- QKV projections (+ FE added to K) ----------------
__global__ __launch_bounds__(256) void k_qkv(
    const float* __restrict__ x, const int* __restrict__ batch,
    const float* __restrict__ Wq, const float* __restrict__ bq,
    const float* __restrict__ Wk, const float* __restrict__ bk,
    const float* __restrict__ Wv, const float* __restrict__ bv,
    const float* __restrict__ FE,
    float* __restrict__ Q, float* __restrict__ Kp, float* __restrict__ V)
{
    __shared__ __align__(16) float xs[16][kHID];
    int row0 = blockIdx.x * 16;
    int tid  = threadIdx.x;

    for (int idx = tid; idx < 16 * 32; idx += 256) {
        int r = idx >> 5, c4 = idx & 31;
        int node = row0 + r;
        float4 v = (node < kN) ? ((const float4*)x)[(size_t)node * 32 + c4]
                               : make_float4(0.f, 0.f, 0.f, 0.f);
        ((float4*)&xs[r][0])[c4] = v;
    }
    __syncthreads();

    int c  = tid & 127;
    int rg = tid >> 7;     // 0 or 1
    float aq[8], ak[8], av[8];
    float bqc = bq[c], bkc = bk[c], bvc = bv[c];
#pragma unroll
    for (int m = 0; m < 8; m++) { aq[m] = bqc; ak[m] = bkc; av[m] = bvc; }

#pragma unroll 4
    for (int k = 0; k < kHID; k++) {
        float wq = Wq[k * kHID + c];
        float wk = Wk[k * kHID + c];
        float wv = Wv[k * kHID + c];
#pragma unroll
        for (int m = 0; m < 8; m++) {
            float xv = xs[m * 2 + rg][k];
            aq[m] = fmaf(xv, wq, aq[m]);
            ak[m] = fmaf(xv, wk, ak[m]);
            av[m] = fmaf(xv, wv, av[m]);
        }
    }
#pragma unroll
    for (int m = 0; m < 8; m++) {
        int node = row0 + m * 2 + rg;
        if (node < kN) {
            int b = batch[node];
            Q[(size_t)node * kHID + c]  = aq[m];
            Kp[(size_t)node * kHID + c] = ak[m] + FE[b * kHID + c];
            V[(size_t)node * kHID + c]  = av[m];
        }
    }
}

// ---------------- CSR build: histogram of src ----------------
__global__ __launch_bounds__(256) void k_hist(const int* __restrict__ ei,
                                              int* __restrict__ count) {
    int e = blockIdx.x * 256 + threadIdx.x;   // grid sized exactly E/256
    atomicAdd(&count[ei[e]], 1);
}

// ---------------- CSR build: exclusive scan of counts (1 block, 1024 thr) ----
__global__ __launch_bounds__(1024) void k_scan(const int* __restrict__ count,
                                               int* __restrict__ rowptr,
                                               int* __restrict__ cursor) {
    __shared__ int wsum[16];
    __shared__ int carry;
    int tid = threadIdx.x;
    int lane = tid & 63, wv = tid >> 6;
    if (tid == 0) carry = 0;
    __syncthreads();
    for (int base = 0; base < kN; base += 1024) {
        int i = base + tid;
        int v = (i < kN) ? count[i] : 0;
        int s = v;
        for (int off = 1; off < 64; off <<= 1) {
            int t = __shfl_up(s, off);
            if (lane >= off) s += t;
        }
        if (lane == 63) wsum[wv] = s;
        __syncthreads();
        if (wv == 0 && lane < 16) {
            int t = wsum[lane];
            for (int off = 1; off < 16; off <<= 1) {
                int u = __shfl_up(t, off);
                if (lane >= off) t += u;
            }
            wsum[lane] = t;
        }
        __syncthreads();
        int waveoff = (wv == 0) ? 0 : wsum[wv - 1];
        int excl = carry + waveoff + (s - v);
        if (i < kN) { rowptr[i] = excl; cursor[i] = excl; }
        __syncthreads();
        if (tid == 0) carry += wsum[15];
        __syncthreads();
    }
    if (tid == 0) rowptr[kN] = carry;   // == E
}

// ---------------- CSR build: fill edge ids ----------------
__global__ __launch_bounds__(256) void k_fill(const int* __restrict__ ei,
                                              int* __restrict__ cursor,
                                              int* __restrict__ eid) {
    int e = blockIdx.x * 256 + threadIdx.x;
    int pos = atomicAdd(&cursor[ei[e]], 1);
    eid[pos] = e;
}

// ---------------- edge scores -> P = exp(QK/4), Z[h] = sum_e P ----------------
__global__ __launch_bounds__(256) void k_scores(
    const int* __restrict__ ei, const float* __restrict__ Q,
    const float* __restrict__ Kp, float* __restrict__ P, float* __restrict__ Z)
{
    int tid = threadIdx.x;
    int h = tid & 7;
    float zsum = 0.f;
    const float4* Q4 = (const float4*)Q;
    const float4* K4 = (const float4*)Kp;
    int stride = gridDim.x * blockDim.x;
    for (int g = blockIdx.x * blockDim.x + tid; g < kItems; g += stride) {
        int e = g >> 3;
        int s = ei[e];
        int d = ei[kE + e];
        const float4* q = Q4 + (size_t)s * 32 + h * 4;
        const float4* k = K4 + (size_t)d * 32 + h * 4;
        float dot = 0.f;
#pragma unroll
        for (int j = 0; j < 4; j++) {
            float4 qa = q[j], ka = k[j];
            dot += qa.x * ka.x + qa.y * ka.y + qa.z * ka.z + qa.w * ka.w;
        }
        float p = __expf(dot * 0.25f);
        P[g] = p;
        zsum += p;
    }
    zsum += __shfl_xor(zsum, 8);
    zsum += __shfl_xor(zsum, 16);
    zsum += __shfl_xor(zsum, 32);
    __shared__ float zl[8];
    if (tid < 8) zl[tid] = 0.f;
    __syncthreads();
    if ((tid & 63) < 8) atomicAdd(&zl[tid & 7], zsum);
    __syncthreads();
    if (tid < 8) atomicAdd(&Z[tid], zl[tid]);
}

// ---------------- aggregation (gather via CSR): agg[n] = sum_{e: src=n} P*V[dst]/Z
__global__ __launch_bounds__(256) void k_agg2(
    const int* __restrict__ ei, const int* __restrict__ rowptr,
    const int* __restrict__ eid, const float* __restrict__ V,
    const float* __restrict__ P, const float* __restrict__ Z,
    float* __restrict__ agg)
{
    __shared__ float invZ[8];
    int tid = threadIdx.x;
    if (tid < 8) invZ[tid] = 1.0f / Z[tid];
    __syncthreads();
    int node = blockIdx.x * 8 + (tid >> 5);   // 8 nodes per block, exact grid
    int c4 = tid & 31;                        // float4 column
    int h = c4 >> 2;
    float iz = invZ[h];
    int beg = rowptr[node], end = rowptr[node + 1];
    float4 acc = make_float4(0.f, 0.f, 0.f, 0.f);
    const float4* V4 = (const float4*)V;
#pragma unroll 2
    for (int i = beg; i < end; ++i) {
        int e = eid[i];
        int d = ei[kE + e];
        float w = P[(size_t)e * 8 + h];
        float4 v = V4[(size_t)d * 32 + c4];
        acc.x = fmaf(w, v.x, acc.x);
        acc.y = fmaf(w, v.y, acc.y);
        acc.z = fmaf(w, v.z, acc.z);
        acc.w = fmaf(w, v.w, acc.w);
    }
    ((float4*)agg)[(size_t)node * 32 + c4] =
        make_float4(acc.x * iz, acc.y * iz, acc.z * iz, acc.w * iz);
}

// ---------------- output: out = x + agg @ Wo + bo ----------------
__global__ __launch_bounds__(256) void k_out(
    const float* __restrict__ agg, const float* __restrict__ Wo,
    const float* __restrict__ bo, const float* __restrict__ x,
    float* __restrict__ out)
{
    __shared__ __align__(16) float as_[16][kHID];
    int row0 = blockIdx.x * 16;
    int tid = threadIdx.x;
    for (int idx = tid; idx < 16 * 32; idx += 256) {
        int r = idx >> 5, c4 = idx & 31;
        int node = row0 + r;
        float4 v = (node < kN) ? ((const float4*)agg)[(size_t)node * 32 + c4]
                               : make_float4(0.f, 0.f, 0.f, 0.f);
        ((float4*)&as_[r][0])[c4] = v;
    }
    __syncthreads();
    int c = tid & 127, rg = tid >> 7;
    float acc[8];
    float boc = bo[c];
#pragma unroll
    for (int m = 0; m < 8; m++) acc[m] = boc;
#pragma unroll 4
    for (int k = 0; k < kHID; k++) {
        float wo = Wo[k * kHID + c];
#pragma unroll
        for (int m = 0; m < 8; m++)
            acc[m] = fmaf(as_[m * 2 + rg][k], wo, acc[m]);
    }
#pragma unroll
    for (int m = 0; m < 8; m++) {
        int node = row0 + m * 2 + rg;
        if (node < kN)
            out[(size_t)node * kHID + c] = x[(size_t)node * kHID + c] + acc[m];
    }
}

extern "C" void kernel_launch(void* const* d_in, const int* in_sizes, int n_in,
                              void* d_out, int out_size, void* d_ws, size_t ws_size,
                              hipStream_t stream) {
    const float* x     = (const float*)d_in[0];
    const int*   ei    = (const int*)d_in[1];
    // d_in[2] = edge_attr (unused by reference)
    const float* fv    = (const float*)d_in[3];
    const int*   batch = (const int*)d_in[4];
    const float* Wq = (const float*)d_in[5];  const float* bq = (const float*)d_in[6];
    const float* Wk = (const float*)d_in[7];  const float* bk = (const float*)d_in[8];
    const float* Wv = (const float*)d_in[9];  const float* bv = (const float*)d_in[10];
    const float* Wf = (const float*)d_in[11]; const float* bf = (const float*)d_in[12];
    const float* Wo = (const float*)d_in[13]; const float* bo = (const float*)d_in[14];

    float* ws  = (float*)d_ws;
    float* Q   = ws + OFF_Q;
    float* Kp  = ws + OFF_K;
    float* V   = ws + OFF_V;
    float* P   = ws + OFF_P;
    float* FE  = ws + OFF_FE;
    float* Z   = ws + OFF_Z;
    int*   cnt    = (int*)(ws + OFF_CNT);
    int*   rowptr = (int*)(ws + OFF_ROWPTR);
    int*   cursor = (int*)(ws + OFF_CURSOR);
    int*   eid    = (int*)(ws + OFF_EID);
    float* agg = ws + OFF_AGG;   // aliases Q (dead after k_scores)
    float* out = (float*)d_out;

    hipMemsetAsync(Z, 0, kNH * sizeof(float), stream);
    hipMemsetAsync(cnt, 0, kN * sizeof(int), stream);

    k_fe<<<kBG, kHID, 0, stream>>>(fv, Wf, bf, FE);

    // CSR build (depends only on edge_index)
    k_hist<<<kE / 256, 256, 0, stream>>>(ei, cnt);
    k_scan<<<1, 1024, 0, stream>>>(cnt, rowptr, cursor);
    k_fill<<<kE / 256, 256, 0, stream>>>(ei, cursor, eid);

    k_qkv<<<(kN + 15) / 16, 256, 0, stream>>>(x, batch, Wq, bq, Wk, bk, Wv, bv,
                                              FE, Q, Kp, V);

    k_scores<<<1280, 256, 0, stream>>>(ei, Q, Kp, P, Z);

    // agg aliases Q; safe: k_scores (consumer of Q) has completed in stream order
    k_agg2<<<kN / 8, 256, 0, stream>>>(ei, rowptr, eid, V, P, Z, agg);

    k_out<<<(kN + 15) / 16, 256, 0, stream>>>(agg, Wo, bo, x, out);
}

// Round 3
// 277.863 us; speedup vs baseline: 17.3307x; 1.3228x over previous
//
#include <hip/hip_runtime.h>

// Problem constants
constexpr int kN   = 40000;
constexpr int kHID = 128;
constexpr int kNH  = 8;
constexpr int kE   = 640000;
constexpr int kBG  = 64;

// ws layout (in 4B units)
constexpr size_t OFF_QF     = 0;                            // N*128 fp32
constexpr size_t OFF_AGG    = (size_t)kN * kHID;            // N*128 fp32
constexpr size_t OFF_KV     = OFF_AGG + (size_t)kN * kHID;  // N*128 uint (bf16 K|V)
constexpr size_t OFF_FE     = OFF_KV + (size_t)kN * kHID;   // BG*128 fp32
constexpr size_t OFF_Z2     = OFF_FE + (size_t)kBG * kHID;  // 16*8 fp32
constexpr size_t OFF_CNT    = OFF_Z2 + 128;                 // N ints
constexpr size_t OFF_ROWPTR = OFF_CNT + kN;                 // N+1 ints
constexpr size_t OFF_CURSOR = OFF_ROWPTR + kN + 1;          // N ints
constexpr size_t OFF_DSTC   = OFF_CURSOR + kN;              // E ints

__device__ __forceinline__ unsigned bf16_rne(float x) {
    unsigned u = __float_as_uint(x);
    return (u + 0x7fffu + ((u >> 16) & 1u)) >> 16;
}

// ---------------- field embedding ----------------
__global__ void k_fe(const float* __restrict__ fv, const float* __restrict__ Wf,
                     const float* __restrict__ bf, float* __restrict__ FE) {
    int g = blockIdx.x;     // 64
    int c = threadIdx.x;    // 128
    float acc = bf[c]
              + fv[g * 3 + 0] * Wf[0 * kHID + c]
              + fv[g * 3 + 1] * Wf[1 * kHID + c]
              + fv[g * 3 + 2] * Wf[2 * kHID + c];
    FE[g * kHID + c] = acc;
}

// ---------------- QKV projections: Qf fp32, KV packed bf16 (K | V<<16) -------
__global__ __launch_bounds__(256) void k_qkv(
    const float* __restrict__ x, const int* __restrict__ batch,
    const float* __restrict__ Wq, const float* __restrict__ bq,
    const float* __restrict__ Wk, const float* __restrict__ bk,
    const float* __restrict__ Wv, const float* __restrict__ bv,
    const float* __restrict__ FE,
    float* __restrict__ Qf, unsigned* __restrict__ KVw)
{
    __shared__ __align__(16) float xs[16][kHID];
    int row0 = blockIdx.x * 16;
    int tid  = threadIdx.x;

    for (int idx = tid; idx < 16 * 32; idx += 256) {
        int r = idx >> 5, c4 = idx & 31;
        int node = row0 + r;
        float4 v = (node < kN) ? ((const float4*)x)[(size_t)node * 32 + c4]
                               : make_float4(0.f, 0.f, 0.f, 0.f);
        ((float4*)&xs[r][0])[c4] = v;
    }
    __syncthreads();

    int c  = tid & 127;
    int rg = tid >> 7;     // 0 or 1
    float aq[8], ak[8], av[8];
    float bqc = bq[c], bkc = bk[c], bvc = bv[c];
#pragma unroll
    for (int m = 0; m < 8; m++) { aq[m] = bqc; ak[m] = bkc; av[m] = bvc; }

#pragma unroll 4
    for (int k = 0; k < kHID; k++) {
        float wq = Wq[k * kHID + c];
        float wk = Wk[k * kHID + c];
        float wv = Wv[k * kHID + c];
#pragma unroll
        for (int m = 0; m < 8; m++) {
            float xv = xs[m * 2 + rg][k];
            aq[m] = fmaf(xv, wq, aq[m]);
            ak[m] = fmaf(xv, wk, ak[m]);
            av[m] = fmaf(xv, wv, av[m]);
        }
    }
#pragma unroll
    for (int m = 0; m < 8; m++) {
        int node = row0 + m * 2 + rg;
        if (node < kN) {
            int b = batch[node];
            Qf[(size_t)node * kHID + c] = aq[m];
            float kk = ak[m] + FE[b * kHID + c];
            KVw[(size_t)node * kHID + c] = bf16_rne(kk) | (bf16_rne(av[m]) << 16);
        }
    }
}

// ---------------- CSR build ----------------
__global__ __launch_bounds__(256) void k_hist(const int* __restrict__ ei,
                                              int* __restrict__ count) {
    int e = blockIdx.x * 256 + threadIdx.x;
    atomicAdd(&count[ei[e]], 1);
}

__global__ __launch_bounds__(1024) void k_scan(const int* __restrict__ count,
                                               int* __restrict__ rowptr,
                                               int* __restrict__ cursor) {
    __shared__ int wsum[16];
    __shared__ int carry;
    int tid = threadIdx.x;
    int lane = tid & 63, wv = tid >> 6;
    if (tid == 0) carry = 0;
    __syncthreads();
    for (int base = 0; base < kN; base += 1024) {
        int i = base + tid;
        int v = (i < kN) ? count[i] : 0;
        int s = v;
        for (int off = 1; off < 64; off <<= 1) {
            int t = __shfl_up(s, off);
            if (lane >= off) s += t;
        }
        if (lane == 63) wsum[wv] = s;
        __syncthreads();
        if (wv == 0 && lane < 16) {
            int t = wsum[lane];
            for (int off = 1; off < 16; off <<= 1) {
                int u = __shfl_up(t, off);
                if (lane >= off) t += u;
            }
            wsum[lane] = t;
        }
        __syncthreads();
        int waveoff = (wv == 0) ? 0 : wsum[wv - 1];
        int excl = carry + waveoff + (s - v);
        if (i < kN) { rowptr[i] = excl; cursor[i] = excl; }
        __syncthreads();
        if (tid == 0) carry += wsum[15];
        __syncthreads();
    }
    if (tid == 0) rowptr[kN] = carry;   // == E
}

__global__ __launch_bounds__(256) void k_fill(const int* __restrict__ ei,
                                              int* __restrict__ cursor,
                                              int* __restrict__ dstc) {
    int e = blockIdx.x * 256 + threadIdx.x;
    int pos = atomicAdd(&cursor[ei[e]], 1);
    dstc[pos] = ei[kE + e];
}

// ---------------- fused edge phase: agg[n] = sum_e exp(q·k/4) * V[dst] -------
// 32 lanes per node; lane c4 owns dims [c4*4, c4*4+4); head h = c4>>2.
__global__ __launch_bounds__(256) void k_edge(
    const int* __restrict__ rowptr, const int* __restrict__ dstc,
    const float* __restrict__ Qf, const unsigned* __restrict__ KVw,
    float* __restrict__ agg, float* __restrict__ Z2)
{
    __shared__ float zl[8];
    int tid = threadIdx.x;
    if (tid < 8) zl[tid] = 0.f;
    __syncthreads();

    int node = blockIdx.x * 8 + (tid >> 5);
    int c4   = tid & 31;
    float4 q = ((const float4*)Qf)[(size_t)node * 32 + c4];
    int beg = rowptr[node], end = rowptr[node + 1];

    const uint4* KV4 = (const uint4*)KVw;
    float4 acc = make_float4(0.f, 0.f, 0.f, 0.f);
    float zsum = 0.f;

    for (int i = beg; i < end; ++i) {
        int d = dstc[i];
        uint4 w = KV4[(size_t)d * 32 + c4];
        float k0 = __uint_as_float(w.x << 16);
        float k1 = __uint_as_float(w.y << 16);
        float k2 = __uint_as_float(w.z << 16);
        float k3 = __uint_as_float(w.w << 16);
        float dot = q.x * k0 + q.y * k1;
        dot = fmaf(q.z, k2, dot);
        dot = fmaf(q.w, k3, dot);
        dot += __shfl_xor(dot, 1);
        dot += __shfl_xor(dot, 2);
        float p = __expf(dot * 0.25f);
        zsum += p;
        float v0 = __uint_as_float(w.x & 0xffff0000u);
        float v1 = __uint_as_float(w.y & 0xffff0000u);
        float v2 = __uint_as_float(w.z & 0xffff0000u);
        float v3 = __uint_as_float(w.w & 0xffff0000u);
        acc.x = fmaf(p, v0, acc.x);
        acc.y = fmaf(p, v1, acc.y);
        acc.z = fmaf(p, v2, acc.z);
        acc.w = fmaf(p, v3, acc.w);
    }

    ((float4*)agg)[(size_t)node * 32 + c4] = acc;

    // Z reduce: one contributing lane per (node, head)
    if ((tid & 3) == 0) atomicAdd(&zl[(c4 >> 2)], zsum);
    __syncthreads();
    if (tid < 8) atomicAdd(&Z2[(blockIdx.x & 15) * 8 + tid], zl[tid]);
}

// ---------------- output: out = x + (agg/Z) @ Wo + bo ----------------
__global__ __launch_bounds__(256) void k_out(
    const float* __restrict__ agg, const float* __restrict__ Z2,
    const float* __restrict__ Wo, const float* __restrict__ bo,
    const float* __restrict__ x, float* __restrict__ out)
{
    __shared__ __align__(16) float as_[16][kHID];
    __shared__ float invZ[8];
    int row0 = blockIdx.x * 16;
    int tid = threadIdx.x;
    if (tid < 8) {
        float z = 0.f;
#pragma unroll
        for (int g = 0; g < 16; g++) z += Z2[g * 8 + tid];
        invZ[tid] = 1.0f / z;
    }
    __syncthreads();
    for (int idx = tid; idx < 16 * 32; idx += 256) {
        int r = idx >> 5, c4 = idx & 31;
        int node = row0 + r;
        float iz = invZ[c4 >> 2];
        float4 v = (node < kN) ? ((const float4*)agg)[(size_t)node * 32 + c4]
                               : make_float4(0.f, 0.f, 0.f, 0.f);
        v.x *= iz; v.y *= iz; v.z *= iz; v.w *= iz;
        ((float4*)&as_[r][0])[c4] = v;
    }
    __syncthreads();
    int c = tid & 127, rg = tid >> 7;
    float acc[8];
    float boc = bo[c];
#pragma unroll
    for (int m = 0; m < 8; m++) acc[m] = boc;
#pragma unroll 4
    for (int k = 0; k < kHID; k++) {
        float wo = Wo[k * kHID + c];
#pragma unroll
        for (int m = 0; m < 8; m++)
            acc[m] = fmaf(as_[m * 2 + rg][k], wo, acc[m]);
    }
#pragma unroll
    for (int m = 0; m < 8; m++) {
        int node = row0 + m * 2 + rg;
        if (node < kN)
            out[(size_t)node * kHID + c] = x[(size_t)node * kHID + c] + acc[m];
    }
}

extern "C" void kernel_launch(void* const* d_in, const int* in_sizes, int n_in,
                              void* d_out, int out_size, void* d_ws, size_t ws_size,
                              hipStream_t stream) {
    const float* x     = (const float*)d_in[0];
    const int*   ei    = (const int*)d_in[1];
    // d_in[2] = edge_attr (unused by reference)
    const float* fv    = (const float*)d_in[3];
    const int*   batch = (const int*)d_in[4];
    const float* Wq = (const float*)d_in[5];  const float* bq = (const float*)d_in[6];
    const float* Wk = (const float*)d_in[7];  const float* bk = (const float*)d_in[8];
    const float* Wv = (const float*)d_in[9];  const float* bv = (const float*)d_in[10];
    const float* Wf = (const float*)d_in[11]; const float* bf = (const float*)d_in[12];
    const float* Wo = (const float*)d_in[13]; const float* bo = (const float*)d_in[14];

    float* ws     = (float*)d_ws;
    float* Qf     = ws + OFF_QF;
    float* agg    = ws + OFF_AGG;
    unsigned* KVw = (unsigned*)(ws + OFF_KV);
    float* FE     = ws + OFF_FE;
    float* Z2     = ws + OFF_Z2;
    int*   cnt    = (int*)(ws + OFF_CNT);
    int*   rowptr = (int*)(ws + OFF_ROWPTR);
    int*   cursor = (int*)(ws + OFF_CURSOR);
    int*   dstc   = (int*)(ws + OFF_DSTC);
    float* out    = (float*)d_out;

    hipMemsetAsync(Z2, 0, 128 * sizeof(float), stream);
    hipMemsetAsync(cnt, 0, kN * sizeof(int), stream);

    k_fe<<<kBG, kHID, 0, stream>>>(fv, Wf, bf, FE);

    // CSR build (depends only on edge_index)
    k_hist<<<kE / 256, 256, 0, stream>>>(ei, cnt);
    k_scan<<<1, 1024, 0, stream>>>(cnt, rowptr, cursor);
    k_fill<<<kE / 256, 256, 0, stream>>>(ei, cursor, dstc);

    k_qkv<<<(kN + 15) / 16, 256, 0, stream>>>(x, batch, Wq, bq, Wk, bk, Wv, bv,
                                              FE, Qf, KVw);

    k_edge<<<kN / 8, 256, 0, stream>>>(rowptr, dstc, Qf, KVw, agg, Z2);

    k_out<<<(kN + 15) / 16, 256, 0, stream>>>(agg, Z2, Wo, bo, x, out);
}

// Round 4
// 209.225 us; speedup vs baseline: 23.0162x; 1.3281x over previous
//
#include <hip/hip_runtime.h>

// Problem constants
constexpr int kN   = 40000;
constexpr int kHID = 128;
constexpr int kE   = 640000;
constexpr int kBG  = 64;
constexpr int kNB  = (kN + 255) / 256;   // 157 scan blocks

// ws layout (4B words)
constexpr size_t OFF_QF     = 0;                             // N*128 f32
constexpr size_t OFF_AGG    = OFF_QF  + (size_t)kN * kHID;   // N*128 f32
constexpr size_t OFF_KV     = OFF_AGG + (size_t)kN * kHID;   // N*128 uint (bf16 K|V)
constexpr size_t OFF_FE     = OFF_KV  + (size_t)kN * kHID;   // BG*128 f32
constexpr size_t OFF_Z2     = OFF_FE  + (size_t)kBG * kHID;  // 16*8 f32
constexpr size_t OFF_WT     = OFF_Z2  + 128;                 // 4*128*128 bf16 = 32768 words
constexpr size_t OFF_CNT    = OFF_WT  + 32768;               // N ints
constexpr size_t OFF_ROWPTR = OFF_CNT + kN;                  // N+1 ints
constexpr size_t OFF_CURSOR = OFF_ROWPTR + kN + 1;           // N ints
constexpr size_t OFF_BSUM   = OFF_CURSOR + kN;               // kNB ints
constexpr size_t OFF_DSTC   = OFF_BSUM + kNB + 1;            // E ints

typedef float f32x4  __attribute__((ext_vector_type(4)));
typedef short bf16x8 __attribute__((ext_vector_type(8)));

__device__ __forceinline__ unsigned short bf16s(float x) {
    unsigned u = __float_as_uint(x);
    return (unsigned short)((u + 0x7fffu + ((u >> 16) & 1u)) >> 16);
}

__device__ __forceinline__ bf16x8 load_a8(const float* p, float scale) {
    float4 f0 = *(const float4*)p;
    float4 f1 = *(const float4*)(p + 4);
    bf16x8 r;
    r[0] = (short)bf16s(f0.x * scale); r[1] = (short)bf16s(f0.y * scale);
    r[2] = (short)bf16s(f0.z * scale); r[3] = (short)bf16s(f0.w * scale);
    r[4] = (short)bf16s(f1.x * scale); r[5] = (short)bf16s(f1.y * scale);
    r[6] = (short)bf16s(f1.z * scale); r[7] = (short)bf16s(f1.w * scale);
    return r;
}

// ---------------- field embedding ----------------
__global__ void k_fe(const float* __restrict__ fv, const float* __restrict__ Wf,
                     const float* __restrict__ bf, float* __restrict__ FE) {
    int g = blockIdx.x;     // 64
    int c = threadIdx.x;    // 128
    float acc = bf[c]
              + fv[g * 3 + 0] * Wf[0 * kHID + c]
              + fv[g * 3 + 1] * Wf[1 * kHID + c]
              + fv[g * 3 + 2] * Wf[2 * kHID + c];
    FE[g * kHID + c] = acc;
}

// ---------------- weight transpose+convert: WT[w][n][k] = bf16(W[k][n]) -----
__global__ __launch_bounds__(256) void k_wt(
    const float* __restrict__ Wq, const float* __restrict__ Wk,
    const float* __restrict__ Wv, const float* __restrict__ Wo,
    unsigned short* __restrict__ WT)
{
    int w   = blockIdx.x >> 4;    // 0..3
    int seg = blockIdx.x & 15;    // 0..15
    const float* W = (w == 0) ? Wq : (w == 1) ? Wk : (w == 2) ? Wv : Wo;
    unsigned short* o = WT + w * 16384;
#pragma unroll
    for (int i = 0; i < 4; i++) {
        int idx = seg * 1024 + i * 256 + threadIdx.x;
        int k = idx >> 7, n = idx & 127;
        o[n * 128 + k] = bf16s(W[idx]);
    }
}

// ---------------- QKV via MFMA: Qf fp32, KV packed bf16 ----------------
// block = 4 waves; wave w owns rows [blk*64 + w*16, +16); K=128 in 4 steps.
__global__ __launch_bounds__(256) void k_qkv(
    const float* __restrict__ x, const int* __restrict__ batch,
    const unsigned short* __restrict__ WT,
    const float* __restrict__ bq, const float* __restrict__ bk,
    const float* __restrict__ bv, const float* __restrict__ FE,
    float* __restrict__ Qf, unsigned* __restrict__ KVw)
{
    int tid = threadIdx.x;
    int wv  = tid >> 6;
    int l   = tid & 63;
    int rl  = l & 15;        // A row / B col / C col within tile
    int kg  = l >> 4;        // k-group 0..3
    int row0 = blockIdx.x * 64 + wv * 16;

    // A fragments (16 rows x 128 k) — registers only
    bf16x8 a[4];
    const float* xrow = x + (size_t)(row0 + rl) * kHID + kg * 8;
#pragma unroll
    for (int kk = 0; kk < 4; kk++) a[kk] = load_a8(xrow + kk * 32, 1.0f);

    // batch ids for this lane's 4 output rows (C rows = kg*4 + r)
    int brow[4];
#pragma unroll
    for (int r = 0; r < 4; r++) brow[r] = batch[row0 + kg * 4 + r];

    unsigned kvhold[8][4];

#pragma unroll
    for (int widx = 0; widx < 3; widx++) {
        const unsigned short* Wb = WT + widx * 16384;
        f32x4 acc[8];
#pragma unroll
        for (int t = 0; t < 8; t++) acc[t] = (f32x4){0.f, 0.f, 0.f, 0.f};
#pragma unroll
        for (int t = 0; t < 8; t++) {
#pragma unroll
            for (int kk = 0; kk < 4; kk++) {
                bf16x8 b = *(const bf16x8*)(Wb + (t * 16 + rl) * 128 + kk * 32 + kg * 8);
                acc[t] = __builtin_amdgcn_mfma_f32_16x16x32_bf16(a[kk], b, acc[t], 0, 0, 0);
            }
        }
        if (widx == 0) {
#pragma unroll
            for (int t = 0; t < 8; t++) {
                float bb = bq[t * 16 + rl];
#pragma unroll
                for (int r = 0; r < 4; r++) {
                    int node = row0 + kg * 4 + r;
                    Qf[(size_t)node * kHID + t * 16 + rl] = acc[t][r] + bb;
                }
            }
        } else if (widx == 1) {
#pragma unroll
            for (int t = 0; t < 8; t++) {
                int c = t * 16 + rl;
                float bb = bk[c];
#pragma unroll
                for (int r = 0; r < 4; r++) {
                    float kval = acc[t][r] + bb + FE[brow[r] * kHID + c];
                    kvhold[t][r] = (unsigned)bf16s(kval);
                }
            }
        } else {
#pragma unroll
            for (int t = 0; t < 8; t++) {
                int c = t * 16 + rl;
                float bb = bv[c];
#pragma unroll
                for (int r = 0; r < 4; r++) {
                    int node = row0 + kg * 4 + r;
                    unsigned vb = (unsigned)bf16s(acc[t][r] + bb);
                    KVw[(size_t)node * kHID + c] = kvhold[t][r] | (vb << 16);
                }
            }
        }
    }
}

// ---------------- CSR build ----------------
__global__ __launch_bounds__(256) void k_hist(const int* __restrict__ ei,
                                              int* __restrict__ count) {
    int e = blockIdx.x * 256 + threadIdx.x;
    atomicAdd(&count[ei[e]], 1);
}

__global__ __launch_bounds__(256) void k_scan1(const int* __restrict__ cnt,
                                               int* __restrict__ rowptr,
                                               int* __restrict__ bsum) {
    int tid = threadIdx.x;
    int i = blockIdx.x * 256 + tid;
    int v = (i < kN) ? cnt[i] : 0;
    int lane = tid & 63, wvi = tid >> 6;
    int s = v;
#pragma unroll
    for (int off = 1; off < 64; off <<= 1) {
        int t = __shfl_up(s, off);
        if (lane >= off) s += t;
    }
    __shared__ int wsums[4];
    if (lane == 63) wsums[wvi] = s;
    __syncthreads();
    int woff = 0;
    if (wvi > 0) woff += wsums[0];
    if (wvi > 1) woff += wsums[1];
    if (wvi > 2) woff += wsums[2];
    if (i < kN) rowptr[i] = woff + s - v;       // block-local exclusive
    if (tid == 255) bsum[blockIdx.x] = woff + s; // block total
}

__global__ __launch_bounds__(256) void k_scan2(int* __restrict__ bsum,
                                               int* __restrict__ rowptr) {
    int tid = threadIdx.x;
    int v = (tid < kNB) ? bsum[tid] : 0;
    int lane = tid & 63, wvi = tid >> 6;
    int s = v;
#pragma unroll
    for (int off = 1; off < 64; off <<= 1) {
        int t = __shfl_up(s, off);
        if (lane >= off) s += t;
    }
    __shared__ int wsums[4];
    if (lane == 63) wsums[wvi] = s;
    __syncthreads();
    int woff = 0;
    if (wvi > 0) woff += wsums[0];
    if (wvi > 1) woff += wsums[1];
    if (wvi > 2) woff += wsums[2];
    if (tid < kNB) bsum[tid] = woff + s - v;    // exclusive block offsets
    if (tid == 0) rowptr[kN] = kE;
}

__global__ __launch_bounds__(256) void k_scan3(const int* __restrict__ bsum,
                                               int* __restrict__ rowptr,
                                               int* __restrict__ cursor) {
    int i = blockIdx.x * 256 + threadIdx.x;
    if (i < kN) {
        int v = rowptr[i] + bsum[blockIdx.x];
        rowptr[i] = v;
        cursor[i] = v;
    }
}

__global__ __launch_bounds__(256) void k_fill(const int* __restrict__ ei,
                                              int* __restrict__ cursor,
                                              int* __restrict__ dstc) {
    int e = blockIdx.x * 256 + threadIdx.x;
    int pos = atomicAdd(&cursor[ei[e]], 1);
    dstc[pos] = ei[kE + e];
}

// ---------------- fused edge phase: agg[n] = sum_e exp(q·k/4) * V[dst] -------
__global__ __launch_bounds__(256) void k_edge(
    const int* __restrict__ rowptr, const int* __restrict__ dstc,
    const float* __restrict__ Qf, const unsigned* __restrict__ KVw,
    float* __restrict__ agg, float* __restrict__ Z2)
{
    __shared__ float zl[8];
    int tid = threadIdx.x;
    if (tid < 8) zl[tid] = 0.f;
    __syncthreads();

    int node = blockIdx.x * 8 + (tid >> 5);
    int c4   = tid & 31;
    float4 q = ((const float4*)Qf)[(size_t)node * 32 + c4];
    int beg = rowptr[node], end = rowptr[node + 1];

    const uint4* KV4 = (const uint4*)KVw;
    float4 acc = make_float4(0.f, 0.f, 0.f, 0.f);
    float zsum = 0.f;

    for (int i = beg; i < end; ++i) {
        int d = dstc[i];
        uint4 w = KV4[(size_t)d * 32 + c4];
        float k0 = __uint_as_float(w.x << 16);
        float k1 = __uint_as_float(w.y << 16);
        float k2 = __uint_as_float(w.z << 16);
        float k3 = __uint_as_float(w.w << 16);
        float dot = q.x * k0 + q.y * k1;
        dot = fmaf(q.z, k2, dot);
        dot = fmaf(q.w, k3, dot);
        dot += __shfl_xor(dot, 1);
        dot += __shfl_xor(dot, 2);
        float p = __expf(dot * 0.25f);
        zsum += p;
        float v0 = __uint_as_float(w.x & 0xffff0000u);
        float v1 = __uint_as_float(w.y & 0xffff0000u);
        float v2 = __uint_as_float(w.z & 0xffff0000u);
        float v3 = __uint_as_float(w.w & 0xffff0000u);
        acc.x = fmaf(p, v0, acc.x);
        acc.y = fmaf(p, v1, acc.y);
        acc.z = fmaf(p, v2, acc.z);
        acc.w = fmaf(p, v3, acc.w);
    }

    ((float4*)agg)[(size_t)node * 32 + c4] = acc;

    if ((tid & 3) == 0) atomicAdd(&zl[(c4 >> 2)], zsum);
    __syncthreads();
    if (tid < 8) atomicAdd(&Z2[(blockIdx.x & 15) * 8 + tid], zl[tid]);
}

// ---------------- output via MFMA: out = x + (agg/Z) @ Wo + bo --------------
__global__ __launch_bounds__(256) void k_out(
    const float* __restrict__ agg, const float* __restrict__ Z2,
    const unsigned short* __restrict__ WTo, const float* __restrict__ bo,
    const float* __restrict__ x, float* __restrict__ out)
{
    __shared__ float invZ[8];
    int tid = threadIdx.x;
    if (tid < 8) {
        float z = 0.f;
#pragma unroll
        for (int g = 0; g < 16; g++) z += Z2[g * 8 + tid];
        invZ[tid] = 1.0f / z;
    }
    __syncthreads();

    int wv = tid >> 6;
    int l  = tid & 63;
    int rl = l & 15;
    int kg = l >> 4;
    int row0 = blockIdx.x * 64 + wv * 16;

    bf16x8 a[4];
    const float* arow = agg + (size_t)(row0 + rl) * kHID + kg * 8;
#pragma unroll
    for (int kk = 0; kk < 4; kk++) {
        int head = (kk * 32 + kg * 8) >> 4;
        a[kk] = load_a8(arow + kk * 32, invZ[head]);
    }

    f32x4 acc[8];
#pragma unroll
    for (int t = 0; t < 8; t++) acc[t] = (f32x4){0.f, 0.f, 0.f, 0.f};
#pragma unroll
    for (int t = 0; t < 8; t++) {
#pragma unroll
        for (int kk = 0; kk < 4; kk++) {
            bf16x8 b = *(const bf16x8*)(WTo + (t * 16 + rl) * 128 + kk * 32 + kg * 8);
            acc[t] = __builtin_amdgcn_mfma_f32_16x16x32_bf16(a[kk], b, acc[t], 0, 0, 0);
        }
    }
#pragma unroll
    for (int t = 0; t < 8; t++) {
        int c = t * 16 + rl;
        float bb = bo[c];
#pragma unroll
        for (int r = 0; r < 4; r++) {
            int node = row0 + kg * 4 + r;
            size_t off = (size_t)node * kHID + c;
            out[off] = x[off] + acc[t][r] + bb;
        }
    }
}

extern "C" void kernel_launch(void* const* d_in, const int* in_sizes, int n_in,
                              void* d_out, int out_size, void* d_ws, size_t ws_size,
                              hipStream_t stream) {
    const float* x     = (const float*)d_in[0];
    const int*   ei    = (const int*)d_in[1];
    // d_in[2] = edge_attr (unused by reference)
    const float* fv    = (const float*)d_in[3];
    const int*   batch = (const int*)d_in[4];
    const float* Wq = (const float*)d_in[5];  const float* bq = (const float*)d_in[6];
    const float* Wk = (const float*)d_in[7];  const float* bk = (const float*)d_in[8];
    const float* Wv = (const float*)d_in[9];  const float* bv = (const float*)d_in[10];
    const float* Wf = (const float*)d_in[11]; const float* bf = (const float*)d_in[12];
    const float* Wo = (const float*)d_in[13]; const float* bo = (const float*)d_in[14];

    float* ws     = (float*)d_ws;
    float* Qf     = ws + OFF_QF;
    float* agg    = ws + OFF_AGG;
    unsigned* KVw = (unsigned*)(ws + OFF_KV);
    float* FE     = ws + OFF_FE;
    float* Z2     = ws + OFF_Z2;
    unsigned short* WT = (unsigned short*)(ws + OFF_WT);
    int*   cnt    = (int*)(ws + OFF_CNT);
    int*   rowptr = (int*)(ws + OFF_ROWPTR);
    int*   cursor = (int*)(ws + OFF_CURSOR);
    int*   bsum   = (int*)(ws + OFF_BSUM);
    int*   dstc   = (int*)(ws + OFF_DSTC);
    float* out    = (float*)d_out;

    hipMemsetAsync(Z2, 0, 128 * sizeof(float), stream);
    hipMemsetAsync(cnt, 0, kN * sizeof(int), stream);

    k_fe<<<kBG, kHID, 0, stream>>>(fv, Wf, bf, FE);
    k_wt<<<64, 256, 0, stream>>>(Wq, Wk, Wv, Wo, WT);

    // CSR build
    k_hist<<<kE / 256, 256, 0, stream>>>(ei, cnt);
    k_scan1<<<kNB, 256, 0, stream>>>(cnt, rowptr, bsum);
    k_scan2<<<1, 256, 0, stream>>>(bsum, rowptr);
    k_scan3<<<kNB, 256, 0, stream>>>(bsum, rowptr, cursor);
    k_fill<<<kE / 256, 256, 0, stream>>>(ei, cursor, dstc);

    k_qkv<<<kN / 64, 256, 0, stream>>>(x, batch, WT, bq, bk, bv, FE, Qf, KVw);

    k_edge<<<kN / 8, 256, 0, stream>>>(rowptr, dstc, Qf, KVw, agg, Z2);

    k_out<<<kN / 64, 256, 0, stream>>>(agg, Z2, WT + 3 * 16384, bo, x, out);
}

// Round 5
// 197.471 us; speedup vs baseline: 24.3863x; 1.0595x over previous
//
#include <hip/hip_runtime.h>

// Problem constants
constexpr int kN   = 40000;
constexpr int kHID = 128;
constexpr int kE   = 640000;
constexpr int kBG  = 64;
constexpr int kNB  = (kN + 255) / 256;   // 157 scan blocks

// ws layout (4B words)
constexpr size_t OFF_QB     = 0;                             // N*128 bf16 = N*64 words
constexpr size_t OFF_AGG    = OFF_QB  + (size_t)kN * 64;     // N*128 f32
constexpr size_t OFF_KV     = OFF_AGG + (size_t)kN * kHID;   // N*128 uint (bf16 K|V)
constexpr size_t OFF_FE     = OFF_KV  + (size_t)kN * kHID;   // BG*128 f32
constexpr size_t OFF_Z2     = OFF_FE  + (size_t)kBG * kHID;  // 16*8 f32
constexpr size_t OFF_WT     = OFF_Z2  + 128;                 // 4*128*128 bf16 = 32768 words
constexpr size_t OFF_CNT    = OFF_WT  + 32768;               // N ints
constexpr size_t OFF_ROWPTR = OFF_CNT + kN;                  // N+1 ints
constexpr size_t OFF_CURSOR = OFF_ROWPTR + kN + 1;           // N ints
constexpr size_t OFF_BSUM   = OFF_CURSOR + kN;               // kNB ints
constexpr size_t OFF_DSTC   = OFF_BSUM + kNB + 1;            // E ints

typedef float f32x4  __attribute__((ext_vector_type(4)));
typedef short bf16x8 __attribute__((ext_vector_type(8)));

__device__ __forceinline__ unsigned short bf16s(float x) {
    unsigned u = __float_as_uint(x);
    return (unsigned short)((u + 0x7fffu + ((u >> 16) & 1u)) >> 16);
}
__device__ __forceinline__ float bfh(unsigned short h) {
    return __uint_as_float(((unsigned)h) << 16);
}

__device__ __forceinline__ bf16x8 load_a8(const float* p, float scale) {
    float4 f0 = *(const float4*)p;
    float4 f1 = *(const float4*)(p + 4);
    bf16x8 r;
    r[0] = (short)bf16s(f0.x * scale); r[1] = (short)bf16s(f0.y * scale);
    r[2] = (short)bf16s(f0.z * scale); r[3] = (short)bf16s(f0.w * scale);
    r[4] = (short)bf16s(f1.x * scale); r[5] = (short)bf16s(f1.y * scale);
    r[6] = (short)bf16s(f1.z * scale); r[7] = (short)bf16s(f1.w * scale);
    return r;
}

// ---------------- prep: WT transpose (blk 0-63), FE + Z2 zero (blk 64),
//                  cnt zero (blk 65-104) ----------------
__global__ __launch_bounds__(256) void k_prep(
    const float* __restrict__ Wq, const float* __restrict__ Wk,
    const float* __restrict__ Wv, const float* __restrict__ Wo,
    const float* __restrict__ fv, const float* __restrict__ Wf,
    const float* __restrict__ bf, unsigned short* __restrict__ WT,
    float* __restrict__ FE, float* __restrict__ Z2, int* __restrict__ cnt)
{
    int blk = blockIdx.x, tid = threadIdx.x;
    if (blk < 64) {
        int w   = blk >> 4;
        int seg = blk & 15;
        const float* W = (w == 0) ? Wq : (w == 1) ? Wk : (w == 2) ? Wv : Wo;
        unsigned short* o = WT + w * 16384;
#pragma unroll
        for (int i = 0; i < 4; i++) {
            int idx = seg * 1024 + i * 256 + tid;
            int k = idx >> 7, n = idx & 127;
            o[n * 128 + k] = bf16s(W[idx]);
        }
    } else if (blk == 64) {
        for (int idx = tid; idx < kBG * kHID; idx += 256) {
            int g = idx >> 7, c = idx & 127;
            FE[idx] = bf[c]
                    + fv[g * 3 + 0] * Wf[0 * kHID + c]
                    + fv[g * 3 + 1] * Wf[1 * kHID + c]
                    + fv[g * 3 + 2] * Wf[2 * kHID + c];
        }
        if (tid < 128) Z2[tid] = 0.f;
    } else {
        for (int i = (blk - 65) * 256 + tid; i < kN; i += 40 * 256) cnt[i] = 0;
    }
}

// ---------------- QKV via MFMA: Qb bf16, KV packed bf16 ----------------
__global__ __launch_bounds__(256) void k_qkv(
    const float* __restrict__ x, const int* __restrict__ batch,
    const unsigned short* __restrict__ WT,
    const float* __restrict__ bq, const float* __restrict__ bk,
    const float* __restrict__ bv, const float* __restrict__ FE,
    unsigned short* __restrict__ Qb, unsigned* __restrict__ KVw)
{
    int tid = threadIdx.x;
    int wv  = tid >> 6;
    int l   = tid & 63;
    int rl  = l & 15;        // A row / B col within tile
    int kg  = l >> 4;        // k-group 0..3
    int row0 = blockIdx.x * 64 + wv * 16;

    bf16x8 a[4];
    const float* xrow = x + (size_t)(row0 + rl) * kHID + kg * 8;
#pragma unroll
    for (int kk = 0; kk < 4; kk++) a[kk] = load_a8(xrow + kk * 32, 1.0f);

    int brow[4];
#pragma unroll
    for (int r = 0; r < 4; r++) brow[r] = batch[row0 + kg * 4 + r];

    unsigned kvhold[8][4];

#pragma unroll
    for (int widx = 0; widx < 3; widx++) {
        const unsigned short* Wb = WT + widx * 16384;
        f32x4 acc[8];
#pragma unroll
        for (int t = 0; t < 8; t++) acc[t] = (f32x4){0.f, 0.f, 0.f, 0.f};
#pragma unroll
        for (int t = 0; t < 8; t++) {
#pragma unroll
            for (int kk = 0; kk < 4; kk++) {
                bf16x8 b = *(const bf16x8*)(Wb + (t * 16 + rl) * 128 + kk * 32 + kg * 8);
                acc[t] = __builtin_amdgcn_mfma_f32_16x16x32_bf16(a[kk], b, acc[t], 0, 0, 0);
            }
        }
        if (widx == 0) {
#pragma unroll
            for (int t = 0; t < 8; t++) {
                float bb = bq[t * 16 + rl];
#pragma unroll
                for (int r = 0; r < 4; r++) {
                    int node = row0 + kg * 4 + r;
                    Qb[(size_t)node * kHID + t * 16 + rl] = bf16s(acc[t][r] + bb);
                }
            }
        } else if (widx == 1) {
#pragma unroll
            for (int t = 0; t < 8; t++) {
                int c = t * 16 + rl;
                float bb = bk[c];
#pragma unroll
                for (int r = 0; r < 4; r++) {
                    float kval = acc[t][r] + bb + FE[brow[r] * kHID + c];
                    kvhold[t][r] = (unsigned)bf16s(kval);
                }
            }
        } else {
#pragma unroll
            for (int t = 0; t < 8; t++) {
                int c = t * 16 + rl;
                float bb = bv[c];
#pragma unroll
                for (int r = 0; r < 4; r++) {
                    int node = row0 + kg * 4 + r;
                    unsigned vb = (unsigned)bf16s(acc[t][r] + bb);
                    KVw[(size_t)node * kHID + c] = kvhold[t][r] | (vb << 16);
                }
            }
        }
    }
}

// ---------------- CSR build ----------------
__global__ __launch_bounds__(256) void k_hist(const int* __restrict__ ei,
                                              int* __restrict__ count) {
    int e = blockIdx.x * 256 + threadIdx.x;
    atomicAdd(&count[ei[e]], 1);
}

__global__ __launch_bounds__(256) void k_scan1(const int* __restrict__ cnt,
                                               int* __restrict__ rowptr,
                                               int* __restrict__ bsum) {
    int tid = threadIdx.x;
    int i = blockIdx.x * 256 + tid;
    int v = (i < kN) ? cnt[i] : 0;
    int lane = tid & 63, wvi = tid >> 6;
    int s = v;
#pragma unroll
    for (int off = 1; off < 64; off <<= 1) {
        int t = __shfl_up(s, off);
        if (lane >= off) s += t;
    }
    __shared__ int wsums[4];
    if (lane == 63) wsums[wvi] = s;
    __syncthreads();
    int woff = 0;
    if (wvi > 0) woff += wsums[0];
    if (wvi > 1) woff += wsums[1];
    if (wvi > 2) woff += wsums[2];
    if (i < kN) rowptr[i] = woff + s - v;
    if (tid == 255) bsum[blockIdx.x] = woff + s;
}

__global__ __launch_bounds__(256) void k_scan2(int* __restrict__ bsum,
                                               int* __restrict__ rowptr) {
    int tid = threadIdx.x;
    int v = (tid < kNB) ? bsum[tid] : 0;
    int lane = tid & 63, wvi = tid >> 6;
    int s = v;
#pragma unroll
    for (int off = 1; off < 64; off <<= 1) {
        int t = __shfl_up(s, off);
        if (lane >= off) s += t;
    }
    __shared__ int wsums[4];
    if (lane == 63) wsums[wvi] = s;
    __syncthreads();
    int woff = 0;
    if (wvi > 0) woff += wsums[0];
    if (wvi > 1) woff += wsums[1];
    if (wvi > 2) woff += wsums[2];
    if (tid < kNB) bsum[tid] = woff + s - v;
    if (tid == 0) rowptr[kN] = kE;
}

__global__ __launch_bounds__(256) void k_scan3(const int* __restrict__ bsum,
                                               int* __restrict__ rowptr,
                                               int* __restrict__ cursor) {
    int i = blockIdx.x * 256 + threadIdx.x;
    if (i < kN) {
        int v = rowptr[i] + bsum[blockIdx.x];
        rowptr[i] = v;
        cursor[i] = v;
    }
}

__global__ __launch_bounds__(256) void k_fill(const int* __restrict__ ei,
                                              int* __restrict__ cursor,
                                              int* __restrict__ dstc) {
    int e = blockIdx.x * 256 + threadIdx.x;
    int pos = atomicAdd(&cursor[ei[e]], 1);
    dstc[pos] = ei[kE + e];
}

// ---------------- fused edge phase ----------------
__device__ __forceinline__ void edge_step(uint4 w, float qx, float qy, float qz,
                                          float qw_, float4& acc, float& zsum) {
    float k0 = __uint_as_float(w.x << 16);
    float k1 = __uint_as_float(w.y << 16);
    float k2 = __uint_as_float(w.z << 16);
    float k3 = __uint_as_float(w.w << 16);
    float dot = qx * k0 + qy * k1;
    dot = fmaf(qz, k2, dot);
    dot = fmaf(qw_, k3, dot);
    dot += __shfl_xor(dot, 1);
    dot += __shfl_xor(dot, 2);
    float p = __expf(dot * 0.25f);
    zsum += p;
    acc.x = fmaf(p, __uint_as_float(w.x & 0xffff0000u), acc.x);
    acc.y = fmaf(p, __uint_as_float(w.y & 0xffff0000u), acc.y);
    acc.z = fmaf(p, __uint_as_float(w.z & 0xffff0000u), acc.z);
    acc.w = fmaf(p, __uint_as_float(w.w & 0xffff0000u), acc.w);
}

__global__ __launch_bounds__(256) void k_edge(
    const int* __restrict__ rowptr, const int* __restrict__ dstc,
    const unsigned short* __restrict__ Qb, const unsigned* __restrict__ KVw,
    float* __restrict__ agg, float* __restrict__ Z2)
{
    __shared__ float zl[8];
    int tid = threadIdx.x;
    if (tid < 8) zl[tid] = 0.f;
    __syncthreads();

    int node = blockIdx.x * 8 + (tid >> 5);
    int c4   = tid & 31;
    ushort4 qw = ((const ushort4*)Qb)[(size_t)node * 32 + c4];
    float qx = bfh(qw.x), qy = bfh(qw.y), qz = bfh(qw.z), qw_ = bfh(qw.w);
    int beg = rowptr[node], end = rowptr[node + 1];

    const uint4* KV4 = (const uint4*)KVw;
    float4 acc = make_float4(0.f, 0.f, 0.f, 0.f);
    float zsum = 0.f;

    int i = beg;
    for (; i + 4 <= end; i += 4) {
        int d0 = dstc[i], d1 = dstc[i + 1], d2 = dstc[i + 2], d3 = dstc[i + 3];
        uint4 w0 = KV4[(size_t)d0 * 32 + c4];
        uint4 w1 = KV4[(size_t)d1 * 32 + c4];
        uint4 w2 = KV4[(size_t)d2 * 32 + c4];
        uint4 w3 = KV4[(size_t)d3 * 32 + c4];
        edge_step(w0, qx, qy, qz, qw_, acc, zsum);
        edge_step(w1, qx, qy, qz, qw_, acc, zsum);
        edge_step(w2, qx, qy, qz, qw_, acc, zsum);
        edge_step(w3, qx, qy, qz, qw_, acc, zsum);
    }
    for (; i < end; ++i) {
        int d = dstc[i];
        uint4 w = KV4[(size_t)d * 32 + c4];
        edge_step(w, qx, qy, qz, qw_, acc, zsum);
    }

    ((float4*)agg)[(size_t)node * 32 + c4] = acc;

    if ((tid & 3) == 0) atomicAdd(&zl[(c4 >> 2)], zsum);
    __syncthreads();
    if (tid < 8) atomicAdd(&Z2[(blockIdx.x & 15) * 8 + tid], zl[tid]);
}

// ---------------- output via MFMA: out = x + (agg/Z) @ Wo + bo --------------
__global__ __launch_bounds__(256) void k_out(
    const float* __restrict__ agg, const float* __restrict__ Z2,
    const unsigned short* __restrict__ WTo, const float* __restrict__ bo,
    const float* __restrict__ x, float* __restrict__ out)
{
    __shared__ float invZ[8];
    int tid = threadIdx.x;
    if (tid < 8) {
        float z = 0.f;
#pragma unroll
        for (int g = 0; g < 16; g++) z += Z2[g * 8 + tid];
        invZ[tid] = 1.0f / z;
    }
    __syncthreads();

    int wv = tid >> 6;
    int l  = tid & 63;
    int rl = l & 15;
    int kg = l >> 4;
    int row0 = blockIdx.x * 64 + wv * 16;

    bf16x8 a[4];
    const float* arow = agg + (size_t)(row0 + rl) * kHID + kg * 8;
#pragma unroll
    for (int kk = 0; kk < 4; kk++) {
        int head = (kk * 32 + kg * 8) >> 4;
        a[kk] = load_a8(arow + kk * 32, invZ[head]);
    }

    f32x4 acc[8];
#pragma unroll
    for (int t = 0; t < 8; t++) acc[t] = (f32x4){0.f, 0.f, 0.f, 0.f};
#pragma unroll
    for (int t = 0; t < 8; t++) {
#pragma unroll
        for (int kk = 0; kk < 4; kk++) {
            bf16x8 b = *(const bf16x8*)(WTo + (t * 16 + rl) * 128 + kk * 32 + kg * 8);
            acc[t] = __builtin_amdgcn_mfma_f32_16x16x32_bf16(a[kk], b, acc[t], 0, 0, 0);
        }
    }
#pragma unroll
    for (int t = 0; t < 8; t++) {
        int c = t * 16 + rl;
        float bb = bo[c];
#pragma unroll
        for (int r = 0; r < 4; r++) {
            int node = row0 + kg * 4 + r;
            size_t off = (size_t)node * kHID + c;
            out[off] = x[off] + acc[t][r] + bb;
        }
    }
}

extern "C" void kernel_launch(void* const* d_in, const int* in_sizes, int n_in,
                              void* d_out, int out_size, void* d_ws, size_t ws_size,
                              hipStream_t stream) {
    const float* x     = (const float*)d_in[0];
    const int*   ei    = (const int*)d_in[1];
    // d_in[2] = edge_attr (unused by reference)
    const float* fv    = (const float*)d_in[3];
    const int*   batch = (const int*)d_in[4];
    const float* Wq = (const float*)d_in[5];  const float* bq = (const float*)d_in[6];
    const float* Wk = (const float*)d_in[7];  const float* bk = (const float*)d_in[8];
    const float* Wv = (const float*)d_in[9];  const float* bv = (const float*)d_in[10];
    const float* Wf = (const float*)d_in[11]; const float* bf = (const float*)d_in[12];
    const float* Wo = (const float*)d_in[13]; const float* bo = (const float*)d_in[14];

    float* ws     = (float*)d_ws;
    unsigned short* Qb = (unsigned short*)(ws + OFF_QB);
    float* agg    = ws + OFF_AGG;
    unsigned* KVw = (unsigned*)(ws + OFF_KV);
    float* FE     = ws + OFF_FE;
    float* Z2     = ws + OFF_Z2;
    unsigned short* WT = (unsigned short*)(ws + OFF_WT);
    int*   cnt    = (int*)(ws + OFF_CNT);
    int*   rowptr = (int*)(ws + OFF_ROWPTR);
    int*   cursor = (int*)(ws + OFF_CURSOR);
    int*   bsum   = (int*)(ws + OFF_BSUM);
    int*   dstc   = (int*)(ws + OFF_DSTC);
    float* out    = (float*)d_out;

    // prep: WT (blk 0-63), FE + Z2 (blk 64), cnt zero (blk 65-104)
    k_prep<<<105, 256, 0, stream>>>(Wq, Wk, Wv, Wo, fv, Wf, bf, WT, FE, Z2, cnt);

    // CSR build
    k_hist<<<kE / 256, 256, 0, stream>>>(ei, cnt);
    k_scan1<<<kNB, 256, 0, stream>>>(cnt, rowptr, bsum);
    k_scan2<<<1, 256, 0, stream>>>(bsum, rowptr);
    k_scan3<<<kNB, 256, 0, stream>>>(bsum, rowptr, cursor);
    k_fill<<<kE / 256, 256, 0, stream>>>(ei, cursor, dstc);

    k_qkv<<<kN / 64, 256, 0, stream>>>(x, batch, WT, bq, bk, bv, FE, Qb, KVw);

    k_edge<<<kN / 8, 256, 0, stream>>>(rowptr, dstc, Qb, KVw, agg, Z2);

    k_out<<<kN / 64, 256, 0, stream>>>(agg, Z2, WT + 3 * 16384, bo, x, out);
}

// Round 6
// 189.230 us; speedup vs baseline: 25.4482x; 1.0435x over previous
//
#include <hip/hip_runtime.h>

// Problem constants
constexpr int kN   = 40000;
constexpr int kHID = 128;
constexpr int kE   = 640000;
constexpr int kBG  = 64;
constexpr int kNB  = (kN + 255) / 256;   // 157 scan blocks

// ws layout (4B words)
constexpr size_t OFF_QB     = 0;                             // N*128 bf16 = N*64 words
constexpr size_t OFF_AGG    = OFF_QB  + (size_t)kN * 64;     // N*128 f32
constexpr size_t OFF_KV     = OFF_AGG + (size_t)kN * kHID;   // N*128 uint (bf16 K|V)
constexpr size_t OFF_FE     = OFF_KV  + (size_t)kN * kHID;   // BG*128 f32
constexpr size_t OFF_Z2     = OFF_FE  + (size_t)kBG * kHID;  // 16*8 f32
constexpr size_t OFF_WT     = OFF_Z2  + 128;                 // 4*128*128 bf16 = 32768 words
constexpr size_t OFF_CNT    = OFF_WT  + 32768;               // N ints
constexpr size_t OFF_ROWPTR = OFF_CNT + kN;                  // N+1 ints
constexpr size_t OFF_CURSOR = OFF_ROWPTR + kN + 1;           // N ints
constexpr size_t OFF_BSUM   = OFF_CURSOR + kN;               // kNB ints
constexpr size_t OFF_DSTC   = OFF_BSUM + kNB + 1;            // E ints

typedef float f32x4  __attribute__((ext_vector_type(4)));
typedef short bf16x8 __attribute__((ext_vector_type(8)));

__device__ __forceinline__ unsigned short bf16s(float x) {
    unsigned u = __float_as_uint(x);
    return (unsigned short)((u + 0x7fffu + ((u >> 16) & 1u)) >> 16);
}
__device__ __forceinline__ float bfh(unsigned short h) {
    return __uint_as_float(((unsigned)h) << 16);
}

__device__ __forceinline__ bf16x8 load_a8(const float* p, float scale) {
    float4 f0 = *(const float4*)p;
    float4 f1 = *(const float4*)(p + 4);
    bf16x8 r;
    r[0] = (short)bf16s(f0.x * scale); r[1] = (short)bf16s(f0.y * scale);
    r[2] = (short)bf16s(f0.z * scale); r[3] = (short)bf16s(f0.w * scale);
    r[4] = (short)bf16s(f1.x * scale); r[5] = (short)bf16s(f1.y * scale);
    r[6] = (short)bf16s(f1.z * scale); r[7] = (short)bf16s(f1.w * scale);
    return r;
}

// ---------------- prep: WT transpose (blk 0-63), FE + Z2 zero (blk 64),
//                  cnt zero (blk 65-104) ----------------
__global__ __launch_bounds__(256) void k_prep(
    const float* __restrict__ Wq, const float* __restrict__ Wk,
    const float* __restrict__ Wv, const float* __restrict__ Wo,
    const float* __restrict__ fv, const float* __restrict__ Wf,
    const float* __restrict__ bf, unsigned short* __restrict__ WT,
    float* __restrict__ FE, float* __restrict__ Z2, int* __restrict__ cnt)
{
    int blk = blockIdx.x, tid = threadIdx.x;
    if (blk < 64) {
        int w   = blk >> 4;
        int seg = blk & 15;
        const float* W = (w == 0) ? Wq : (w == 1) ? Wk : (w == 2) ? Wv : Wo;
        unsigned short* o = WT + w * 16384;
#pragma unroll
        for (int i = 0; i < 4; i++) {
            int idx = seg * 1024 + i * 256 + tid;
            int k = idx >> 7, n = idx & 127;
            o[n * 128 + k] = bf16s(W[idx]);
        }
    } else if (blk == 64) {
        for (int idx = tid; idx < kBG * kHID; idx += 256) {
            int g = idx >> 7, c = idx & 127;
            FE[idx] = bf[c]
                    + fv[g * 3 + 0] * Wf[0 * kHID + c]
                    + fv[g * 3 + 1] * Wf[1 * kHID + c]
                    + fv[g * 3 + 2] * Wf[2 * kHID + c];
        }
        if (tid < 128) Z2[tid] = 0.f;
    } else {
        for (int i = (blk - 65) * 256 + tid; i < kN; i += 40 * 256) cnt[i] = 0;
    }
}

// ---------------- QKV via MFMA, column-split x2 ----------------
// blockIdx.x = rowblk*2 + colh; wave owns 16 rows x 64 cols, all 3 weights.
__global__ __launch_bounds__(256) void k_qkv(
    const float* __restrict__ x, const int* __restrict__ batch,
    const unsigned short* __restrict__ WT,
    const float* __restrict__ bq, const float* __restrict__ bk,
    const float* __restrict__ bv, const float* __restrict__ FE,
    unsigned short* __restrict__ Qb, unsigned* __restrict__ KVw)
{
    int tid  = threadIdx.x;
    int wv   = tid >> 6;
    int l    = tid & 63;
    int rl   = l & 15;
    int kg   = l >> 4;
    int colh = blockIdx.x & 1;
    int row0 = (blockIdx.x >> 1) * 64 + wv * 16;

    bf16x8 a[4];
    const float* xrow = x + (size_t)(row0 + rl) * kHID + kg * 8;
#pragma unroll
    for (int kk = 0; kk < 4; kk++) a[kk] = load_a8(xrow + kk * 32, 1.0f);

    int brow[4];
#pragma unroll
    for (int r = 0; r < 4; r++) brow[r] = batch[row0 + kg * 4 + r];

    unsigned kvhold[4][4];

#pragma unroll
    for (int widx = 0; widx < 3; widx++) {
        const unsigned short* Wb = WT + widx * 16384;
        f32x4 acc[4];
#pragma unroll
        for (int t = 0; t < 4; t++) acc[t] = (f32x4){0.f, 0.f, 0.f, 0.f};
#pragma unroll
        for (int t = 0; t < 4; t++) {
            int c = (colh * 4 + t) * 16 + rl;
#pragma unroll
            for (int kk = 0; kk < 4; kk++) {
                bf16x8 b = *(const bf16x8*)(Wb + c * 128 + kk * 32 + kg * 8);
                acc[t] = __builtin_amdgcn_mfma_f32_16x16x32_bf16(a[kk], b, acc[t], 0, 0, 0);
            }
        }
        if (widx == 0) {
#pragma unroll
            for (int t = 0; t < 4; t++) {
                int c = (colh * 4 + t) * 16 + rl;
                float bb = bq[c];
#pragma unroll
                for (int r = 0; r < 4; r++) {
                    int node = row0 + kg * 4 + r;
                    Qb[(size_t)node * kHID + c] = bf16s(acc[t][r] + bb);
                }
            }
        } else if (widx == 1) {
#pragma unroll
            for (int t = 0; t < 4; t++) {
                int c = (colh * 4 + t) * 16 + rl;
                float bb = bk[c];
#pragma unroll
                for (int r = 0; r < 4; r++) {
                    float kval = acc[t][r] + bb + FE[brow[r] * kHID + c];
                    kvhold[t][r] = (unsigned)bf16s(kval);
                }
            }
        } else {
#pragma unroll
            for (int t = 0; t < 4; t++) {
                int c = (colh * 4 + t) * 16 + rl;
                float bb = bv[c];
#pragma unroll
                for (int r = 0; r < 4; r++) {
                    int node = row0 + kg * 4 + r;
                    unsigned vb = (unsigned)bf16s(acc[t][r] + bb);
                    KVw[(size_t)node * kHID + c] = kvhold[t][r] | (vb << 16);
                }
            }
        }
    }
}

// ---------------- CSR build ----------------
__global__ __launch_bounds__(256) void k_hist(const int* __restrict__ ei,
                                              int* __restrict__ count) {
    int e = blockIdx.x * 256 + threadIdx.x;
    atomicAdd(&count[ei[e]], 1);
}

__global__ __launch_bounds__(256) void k_scan1(const int* __restrict__ cnt,
                                               int* __restrict__ rowptr,
                                               int* __restrict__ bsum) {
    int tid = threadIdx.x;
    int i = blockIdx.x * 256 + tid;
    int v = (i < kN) ? cnt[i] : 0;
    int lane = tid & 63, wvi = tid >> 6;
    int s = v;
#pragma unroll
    for (int off = 1; off < 64; off <<= 1) {
        int t = __shfl_up(s, off);
        if (lane >= off) s += t;
    }
    __shared__ int wsums[4];
    if (lane == 63) wsums[wvi] = s;
    __syncthreads();
    int woff = 0;
    if (wvi > 0) woff += wsums[0];
    if (wvi > 1) woff += wsums[1];
    if (wvi > 2) woff += wsums[2];
    if (i < kN) rowptr[i] = woff + s - v;
    if (tid == 255) bsum[blockIdx.x] = woff + s;
}

__global__ __launch_bounds__(256) void k_scan2(int* __restrict__ bsum,
                                               int* __restrict__ rowptr) {
    int tid = threadIdx.x;
    int v = (tid < kNB) ? bsum[tid] : 0;
    int lane = tid & 63, wvi = tid >> 6;
    int s = v;
#pragma unroll
    for (int off = 1; off < 64; off <<= 1) {
        int t = __shfl_up(s, off);
        if (lane >= off) s += t;
    }
    __shared__ int wsums[4];
    if (lane == 63) wsums[wvi] = s;
    __syncthreads();
    int woff = 0;
    if (wvi > 0) woff += wsums[0];
    if (wvi > 1) woff += wsums[1];
    if (wvi > 2) woff += wsums[2];
    if (tid < kNB) bsum[tid] = woff + s - v;
    if (tid == 0) rowptr[kN] = kE;
}

__global__ __launch_bounds__(256) void k_scan3(const int* __restrict__ bsum,
                                               int* __restrict__ rowptr,
                                               int* __restrict__ cursor) {
    int i = blockIdx.x * 256 + threadIdx.x;
    if (i < kN) {
        int v = rowptr[i] + bsum[blockIdx.x];
        rowptr[i] = v;
        cursor[i] = v;
    }
}

__global__ __launch_bounds__(256) void k_fill(const int* __restrict__ ei,
                                              int* __restrict__ cursor,
                                              int* __restrict__ dstc) {
    int e = blockIdx.x * 256 + threadIdx.x;
    int pos = atomicAdd(&cursor[ei[e]], 1);
    dstc[pos] = ei[kE + e];
}

// ---------------- fused edge phase ----------------
__device__ __forceinline__ void edge_step(uint4 w, float qx, float qy, float qz,
                                          float qw_, float4& acc, float& zsum) {
    float k0 = __uint_as_float(w.x << 16);
    float k1 = __uint_as_float(w.y << 16);
    float k2 = __uint_as_float(w.z << 16);
    float k3 = __uint_as_float(w.w << 16);
    float dot = qx * k0 + qy * k1;
    dot = fmaf(qz, k2, dot);
    dot = fmaf(qw_, k3, dot);
    dot += __shfl_xor(dot, 1);
    dot += __shfl_xor(dot, 2);
    float p = __expf(dot * 0.25f);
    zsum += p;
    acc.x = fmaf(p, __uint_as_float(w.x & 0xffff0000u), acc.x);
    acc.y = fmaf(p, __uint_as_float(w.y & 0xffff0000u), acc.y);
    acc.z = fmaf(p, __uint_as_float(w.z & 0xffff0000u), acc.z);
    acc.w = fmaf(p, __uint_as_float(w.w & 0xffff0000u), acc.w);
}

__global__ __launch_bounds__(256) void k_edge(
    const int* __restrict__ rowptr, const int* __restrict__ dstc,
    const unsigned short* __restrict__ Qb, const unsigned* __restrict__ KVw,
    float* __restrict__ agg, float* __restrict__ Z2)
{
    __shared__ float zl[8];
    int tid = threadIdx.x;
    if (tid < 8) zl[tid] = 0.f;
    __syncthreads();

    int node = blockIdx.x * 8 + (tid >> 5);
    int c4   = tid & 31;
    ushort4 qw = ((const ushort4*)Qb)[(size_t)node * 32 + c4];
    float qx = bfh(qw.x), qy = bfh(qw.y), qz = bfh(qw.z), qw_ = bfh(qw.w);
    int beg = rowptr[node], end = rowptr[node + 1];

    const uint4* KV4 = (const uint4*)KVw;
    float4 acc = make_float4(0.f, 0.f, 0.f, 0.f);
    float zsum = 0.f;

    int i = beg;
    for (; i + 8 <= end; i += 8) {
        int dd[8];
#pragma unroll
        for (int j = 0; j < 8; j++) dd[j] = dstc[i + j];
        uint4 w[8];
#pragma unroll
        for (int j = 0; j < 8; j++) w[j] = KV4[(size_t)dd[j] * 32 + c4];
#pragma unroll
        for (int j = 0; j < 8; j++) edge_step(w[j], qx, qy, qz, qw_, acc, zsum);
    }
    for (; i + 4 <= end; i += 4) {
        int dd[4];
#pragma unroll
        for (int j = 0; j < 4; j++) dd[j] = dstc[i + j];
        uint4 w[4];
#pragma unroll
        for (int j = 0; j < 4; j++) w[j] = KV4[(size_t)dd[j] * 32 + c4];
#pragma unroll
        for (int j = 0; j < 4; j++) edge_step(w[j], qx, qy, qz, qw_, acc, zsum);
    }
    for (; i < end; ++i) {
        uint4 w = KV4[(size_t)dstc[i] * 32 + c4];
        edge_step(w, qx, qy, qz, qw_, acc, zsum);
    }

    ((float4*)agg)[(size_t)node * 32 + c4] = acc;

    if ((tid & 3) == 0) atomicAdd(&zl[(c4 >> 2)], zsum);
    __syncthreads();
    if (tid < 8) atomicAdd(&Z2[(blockIdx.x & 15) * 8 + tid], zl[tid]);
}

// ---------------- output via MFMA, column-split x2 ----------------
__global__ __launch_bounds__(256) void k_out(
    const float* __restrict__ agg, const float* __restrict__ Z2,
    const unsigned short* __restrict__ WTo, const float* __restrict__ bo,
    const float* __restrict__ x, float* __restrict__ out)
{
    __shared__ float invZ[8];
    int tid = threadIdx.x;
    if (tid < 8) {
        float z = 0.f;
#pragma unroll
        for (int g = 0; g < 16; g++) z += Z2[g * 8 + tid];
        invZ[tid] = 1.0f / z;
    }
    __syncthreads();

    int wv   = tid >> 6;
    int l    = tid & 63;
    int rl   = l & 15;
    int kg   = l >> 4;
    int colh = blockIdx.x & 1;
    int row0 = (blockIdx.x >> 1) * 64 + wv * 16;

    bf16x8 a[4];
    const float* arow = agg + (size_t)(row0 + rl) * kHID + kg * 8;
#pragma unroll
    for (int kk = 0; kk < 4; kk++) {
        int head = (kk * 32 + kg * 8) >> 4;
        a[kk] = load_a8(arow + kk * 32, invZ[head]);
    }

    f32x4 acc[4];
#pragma unroll
    for (int t = 0; t < 4; t++) acc[t] = (f32x4){0.f, 0.f, 0.f, 0.f};
#pragma unroll
    for (int t = 0; t < 4; t++) {
        int c = (colh * 4 + t) * 16 + rl;
#pragma unroll
        for (int kk = 0; kk < 4; kk++) {
            bf16x8 b = *(const bf16x8*)(WTo + c * 128 + kk * 32 + kg * 8);
            acc[t] = __builtin_amdgcn_mfma_f32_16x16x32_bf16(a[kk], b, acc[t], 0, 0, 0);
        }
    }
#pragma unroll
    for (int t = 0; t < 4; t++) {
        int c = (colh * 4 + t) * 16 + rl;
        float bb = bo[c];
#pragma unroll
        for (int r = 0; r < 4; r++) {
            int node = row0 + kg * 4 + r;
            size_t off = (size_t)node * kHID + c;
            out[off] = x[off] + acc[t][r] + bb;
        }
    }
}

extern "C" void kernel_launch(void* const* d_in, const int* in_sizes, int n_in,
                              void* d_out, int out_size, void* d_ws, size_t ws_size,
                              hipStream_t stream) {
    const float* x     = (const float*)d_in[0];
    const int*   ei    = (const int*)d_in[1];
    // d_in[2] = edge_attr (unused by reference)
    const float* fv    = (const float*)d_in[3];
    const int*   batch = (const int*)d_in[4];
    const float* Wq = (const float*)d_in[5];  const float* bq = (const float*)d_in[6];
    const float* Wk = (const float*)d_in[7];  const float* bk = (const float*)d_in[8];
    const float* Wv = (const float*)d_in[9];  const float* bv = (const float*)d_in[10];
    const float* Wf = (const float*)d_in[11]; const float* bf = (const float*)d_in[12];
    const float* Wo = (const float*)d_in[13]; const float* bo = (const float*)d_in[14];

    float* ws     = (float*)d_ws;
    unsigned short* Qb = (unsigned short*)(ws + OFF_QB);
    float* agg    = ws + OFF_AGG;
    unsigned* KVw = (unsigned*)(ws + OFF_KV);
    float* FE     = ws + OFF_FE;
    float* Z2     = ws + OFF_Z2;
    unsigned short* WT = (unsigned short*)(ws + OFF_WT);
    int*   cnt    = (int*)(ws + OFF_CNT);
    int*   rowptr = (int*)(ws + OFF_ROWPTR);
    int*   cursor = (int*)(ws + OFF_CURSOR);
    int*   bsum   = (int*)(ws + OFF_BSUM);
    int*   dstc   = (int*)(ws + OFF_DSTC);
    float* out    = (float*)d_out;

    k_prep<<<105, 256, 0, stream>>>(Wq, Wk, Wv, Wo, fv, Wf, bf, WT, FE, Z2, cnt);

    // CSR build
    k_hist<<<kE / 256, 256, 0, stream>>>(ei, cnt);
    k_scan1<<<kNB, 256, 0, stream>>>(cnt, rowptr, bsum);
    k_scan2<<<1, 256, 0, stream>>>(bsum, rowptr);
    k_scan3<<<kNB, 256, 0, stream>>>(bsum, rowptr, cursor);
    k_fill<<<kE / 256, 256, 0, stream>>>(ei, cursor, dstc);

    k_qkv<<<(kN / 64) * 2, 256, 0, stream>>>(x, batch, WT, bq, bk, bv, FE, Qb, KVw);

    k_edge<<<kN / 8, 256, 0, stream>>>(rowptr, dstc, Qb, KVw, agg, Z2);

    k_out<<<(kN / 64) * 2, 256, 0, stream>>>(agg, Z2, WT + 3 * 16384, bo, x, out);
}

// Round 7
// 186.702 us; speedup vs baseline: 25.7928x; 1.0135x over previous
//
#include <hip/hip_runtime.h>

// Problem constants
constexpr int kN   = 40000;
constexpr int kHID = 128;
constexpr int kE   = 640000;
constexpr int kBG  = 64;
constexpr int kNB  = (kN + 255) / 256;   // 157 scan blocks

// ws layout (4B words)
constexpr size_t OFF_QB     = 0;                             // N*128 bf16 = N*64 words
constexpr size_t OFF_AGG    = OFF_QB  + (size_t)kN * 64;     // N*128 f32
constexpr size_t OFF_KV     = OFF_AGG + (size_t)kN * kHID;   // N*128 uint (bf16 K|V)
constexpr size_t OFF_FE     = OFF_KV  + (size_t)kN * kHID;   // BG*128 f32
constexpr size_t OFF_Z2     = OFF_FE  + (size_t)kBG * kHID;  // 16*8 f32
constexpr size_t OFF_WT     = OFF_Z2  + 128;                 // 4*128*128 bf16 = 32768 words
constexpr size_t OFF_CNT    = OFF_WT  + 32768;               // N ints
constexpr size_t OFF_ROWPTR = OFF_CNT + kN;                  // N+1 ints
constexpr size_t OFF_CURSOR = OFF_ROWPTR + kN + 1;           // N ints
constexpr size_t OFF_BSUM   = OFF_CURSOR + kN;               // kNB ints
constexpr size_t OFF_DSTC   = OFF_BSUM + kNB + 1;            // E ints

typedef float f32x4  __attribute__((ext_vector_type(4)));
typedef short bf16x8 __attribute__((ext_vector_type(8)));

__device__ __forceinline__ unsigned short bf16s(float x) {
    unsigned u = __float_as_uint(x);
    return (unsigned short)((u + 0x7fffu + ((u >> 16) & 1u)) >> 16);
}
__device__ __forceinline__ float bfh(unsigned short h) {
    return __uint_as_float(((unsigned)h) << 16);
}

__device__ __forceinline__ bf16x8 load_a8(const float* p, float scale) {
    float4 f0 = *(const float4*)p;
    float4 f1 = *(const float4*)(p + 4);
    bf16x8 r;
    r[0] = (short)bf16s(f0.x * scale); r[1] = (short)bf16s(f0.y * scale);
    r[2] = (short)bf16s(f0.z * scale); r[3] = (short)bf16s(f0.w * scale);
    r[4] = (short)bf16s(f1.x * scale); r[5] = (short)bf16s(f1.y * scale);
    r[6] = (short)bf16s(f1.z * scale); r[7] = (short)bf16s(f1.w * scale);
    return r;
}

// ---------------- prep: WT transpose (blk 0-63), FE + Z2 zero (blk 64),
//                  cnt zero (blk 65-104) ----------------
__global__ __launch_bounds__(256) void k_prep(
    const float* __restrict__ Wq, const float* __restrict__ Wk,
    const float* __restrict__ Wv, const float* __restrict__ Wo,
    const float* __restrict__ fv, const float* __restrict__ Wf,
    const float* __restrict__ bf, unsigned short* __restrict__ WT,
    float* __restrict__ FE, float* __restrict__ Z2, int* __restrict__ cnt)
{
    int blk = blockIdx.x, tid = threadIdx.x;
    if (blk < 64) {
        int w   = blk >> 4;
        int seg = blk & 15;
        const float* W = (w == 0) ? Wq : (w == 1) ? Wk : (w == 2) ? Wv : Wo;
        unsigned short* o = WT + w * 16384;
#pragma unroll
        for (int i = 0; i < 4; i++) {
            int idx = seg * 1024 + i * 256 + tid;
            int k = idx >> 7, n = idx & 127;
            o[n * 128 + k] = bf16s(W[idx]);
        }
    } else if (blk == 64) {
        for (int idx = tid; idx < kBG * kHID; idx += 256) {
            int g = idx >> 7, c = idx & 127;
            FE[idx] = bf[c]
                    + fv[g * 3 + 0] * Wf[0 * kHID + c]
                    + fv[g * 3 + 1] * Wf[1 * kHID + c]
                    + fv[g * 3 + 2] * Wf[2 * kHID + c];
        }
        if (tid < 128) Z2[tid] = 0.f;
    } else {
        for (int i = (blk - 65) * 256 + tid; i < kN; i += 40 * 256) cnt[i] = 0;
    }
}

// ---------------- QKV via MFMA, column-split x2 ----------------
__global__ __launch_bounds__(256) void k_qkv(
    const float* __restrict__ x, const int* __restrict__ batch,
    const unsigned short* __restrict__ WT,
    const float* __restrict__ bq, const float* __restrict__ bk,
    const float* __restrict__ bv, const float* __restrict__ FE,
    unsigned short* __restrict__ Qb, unsigned* __restrict__ KVw)
{
    int tid  = threadIdx.x;
    int wv   = tid >> 6;
    int l    = tid & 63;
    int rl   = l & 15;
    int kg   = l >> 4;
    int colh = blockIdx.x & 1;
    int row0 = (blockIdx.x >> 1) * 64 + wv * 16;

    bf16x8 a[4];
    const float* xrow = x + (size_t)(row0 + rl) * kHID + kg * 8;
#pragma unroll
    for (int kk = 0; kk < 4; kk++) a[kk] = load_a8(xrow + kk * 32, 1.0f);

    int brow[4];
#pragma unroll
    for (int r = 0; r < 4; r++) brow[r] = batch[row0 + kg * 4 + r];

    unsigned kvhold[4][4];

#pragma unroll
    for (int widx = 0; widx < 3; widx++) {
        const unsigned short* Wb = WT + widx * 16384;
        f32x4 acc[4];
#pragma unroll
        for (int t = 0; t < 4; t++) acc[t] = (f32x4){0.f, 0.f, 0.f, 0.f};
#pragma unroll
        for (int t = 0; t < 4; t++) {
            int c = (colh * 4 + t) * 16 + rl;
#pragma unroll
            for (int kk = 0; kk < 4; kk++) {
                bf16x8 b = *(const bf16x8*)(Wb + c * 128 + kk * 32 + kg * 8);
                acc[t] = __builtin_amdgcn_mfma_f32_16x16x32_bf16(a[kk], b, acc[t], 0, 0, 0);
            }
        }
        if (widx == 0) {
#pragma unroll
            for (int t = 0; t < 4; t++) {
                int c = (colh * 4 + t) * 16 + rl;
                float bb = bq[c];
#pragma unroll
                for (int r = 0; r < 4; r++) {
                    int node = row0 + kg * 4 + r;
                    Qb[(size_t)node * kHID + c] = bf16s(acc[t][r] + bb);
                }
            }
        } else if (widx == 1) {
#pragma unroll
            for (int t = 0; t < 4; t++) {
                int c = (colh * 4 + t) * 16 + rl;
                float bb = bk[c];
#pragma unroll
                for (int r = 0; r < 4; r++) {
                    float kval = acc[t][r] + bb + FE[brow[r] * kHID + c];
                    kvhold[t][r] = (unsigned)bf16s(kval);
                }
            }
        } else {
#pragma unroll
            for (int t = 0; t < 4; t++) {
                int c = (colh * 4 + t) * 16 + rl;
                float bb = bv[c];
#pragma unroll
                for (int r = 0; r < 4; r++) {
                    int node = row0 + kg * 4 + r;
                    unsigned vb = (unsigned)bf16s(acc[t][r] + bb);
                    KVw[(size_t)node * kHID + c] = kvhold[t][r] | (vb << 16);
                }
            }
        }
    }
}

// ---------------- CSR build ----------------
__global__ __launch_bounds__(256) void k_hist(const int* __restrict__ ei,
                                              int* __restrict__ count) {
    int e = blockIdx.x * 256 + threadIdx.x;
    atomicAdd(&count[ei[e]], 1);
}

__global__ __launch_bounds__(256) void k_scan1(const int* __restrict__ cnt,
                                               int* __restrict__ rowptr,
                                               int* __restrict__ bsum) {
    int tid = threadIdx.x;
    int i = blockIdx.x * 256 + tid;
    int v = (i < kN) ? cnt[i] : 0;
    int lane = tid & 63, wvi = tid >> 6;
    int s = v;
#pragma unroll
    for (int off = 1; off < 64; off <<= 1) {
        int t = __shfl_up(s, off);
        if (lane >= off) s += t;
    }
    __shared__ int wsums[4];
    if (lane == 63) wsums[wvi] = s;
    __syncthreads();
    int woff = 0;
    if (wvi > 0) woff += wsums[0];
    if (wvi > 1) woff += wsums[1];
    if (wvi > 2) woff += wsums[2];
    if (i < kN) rowptr[i] = woff + s - v;
    if (tid == 255) bsum[blockIdx.x] = woff + s;
}

// fused scan2+scan3: each block reduces bsum[0..blockIdx) and applies offset
__global__ __launch_bounds__(256) void k_scan23(
    const int* __restrict__ bsum, int* __restrict__ rowptr,
    int* __restrict__ cursor)
{
    __shared__ int ws_[4];
    int tid = threadIdx.x;
    int v = (tid < kNB && tid < (int)blockIdx.x) ? bsum[tid] : 0;
    int s = v;
#pragma unroll
    for (int off = 1; off < 64; off <<= 1) s += __shfl_xor(s, off);
    if ((tid & 63) == 0) ws_[tid >> 6] = s;
    __syncthreads();
    int offset = ws_[0] + ws_[1] + ws_[2] + ws_[3];
    int i = blockIdx.x * 256 + tid;
    if (i < kN) {
        int r = rowptr[i] + offset;
        rowptr[i] = r;
        cursor[i] = r;
    }
    if (blockIdx.x == 0 && tid == 0) rowptr[kN] = kE;
}

__global__ __launch_bounds__(256) void k_fill(const int* __restrict__ ei,
                                              int* __restrict__ cursor,
                                              int* __restrict__ dstc) {
    int e = blockIdx.x * 256 + threadIdx.x;
    int pos = atomicAdd(&cursor[ei[e]], 1);
    dstc[pos] = ei[kE + e];
}

// ---------------- fused edge phase ----------------
// One node per wave64; halves process even/odd edges of the SAME node.
__device__ __forceinline__ void edge_step(uint4 w, float qx, float qy, float qz,
                                          float qw_, float4& acc, float& zsum) {
    float dot = qx * __uint_as_float(w.x << 16)
              + qy * __uint_as_float(w.y << 16);
    dot = fmaf(qz, __uint_as_float(w.z << 16), dot);
    dot = fmaf(qw_, __uint_as_float(w.w << 16), dot);
    dot += __shfl_xor(dot, 1);
    dot += __shfl_xor(dot, 2);
    float p = __expf(dot);
    zsum += p;
    acc.x = fmaf(p, __uint_as_float(w.x & 0xffff0000u), acc.x);
    acc.y = fmaf(p, __uint_as_float(w.y & 0xffff0000u), acc.y);
    acc.z = fmaf(p, __uint_as_float(w.z & 0xffff0000u), acc.z);
    acc.w = fmaf(p, __uint_as_float(w.w & 0xffff0000u), acc.w);
}

__global__ __launch_bounds__(256) void k_edge(
    const int* __restrict__ rowptr, const int* __restrict__ dstc,
    const unsigned short* __restrict__ Qb, const unsigned* __restrict__ KVw,
    float* __restrict__ agg, float* __restrict__ Z2)
{
    __shared__ float zl[8];
    int tid = threadIdx.x;
    if (tid < 8) zl[tid] = 0.f;
    __syncthreads();

    int wv   = tid >> 6;
    int lane = tid & 63;
    int half = lane >> 5;
    int c4   = lane & 31;
    int node = blockIdx.x * 4 + wv;

    ushort4 qw = ((const ushort4*)Qb)[(size_t)node * 32 + c4];
    // pre-scale by 1/sqrt(16)/... = 0.25 (exact pow2): saves a mul per edge
    float qx  = bfh(qw.x) * 0.25f, qy  = bfh(qw.y) * 0.25f;
    float qz  = bfh(qw.z) * 0.25f, qw_ = bfh(qw.w) * 0.25f;
    int beg = rowptr[node], end = rowptr[node + 1];

    const uint4* KV4 = (const uint4*)KVw;
    float4 acc = make_float4(0.f, 0.f, 0.f, 0.f);
    float zsum = 0.f;

    int i = beg + half;            // this half's first edge (stride 2)
    for (; i + 2 < end; i += 4) {  // 2-unrolled: edges i and i+2
        int d0 = dstc[i], d1 = dstc[i + 2];
        uint4 w0 = KV4[(size_t)d0 * 32 + c4];
        uint4 w1 = KV4[(size_t)d1 * 32 + c4];
        edge_step(w0, qx, qy, qz, qw_, acc, zsum);
        edge_step(w1, qx, qy, qz, qw_, acc, zsum);
    }
    if (i < end) {
        uint4 w = KV4[(size_t)dstc[i] * 32 + c4];
        edge_step(w, qx, qy, qz, qw_, acc, zsum);
    }

    // combine the two halves (same node)
    acc.x += __shfl_xor(acc.x, 32);
    acc.y += __shfl_xor(acc.y, 32);
    acc.z += __shfl_xor(acc.z, 32);
    acc.w += __shfl_xor(acc.w, 32);
    if (half == 0)
        ((float4*)agg)[(size_t)node * 32 + c4] = acc;

    if ((lane & 3) == 0) atomicAdd(&zl[c4 >> 2], zsum);
    __syncthreads();
    if (tid < 8) atomicAdd(&Z2[(blockIdx.x & 15) * 8 + tid], zl[tid]);
}

// ---------------- output via MFMA, column-split x2 ----------------
__global__ __launch_bounds__(256) void k_out(
    const float* __restrict__ agg, const float* __restrict__ Z2,
    const unsigned short* __restrict__ WTo, const float* __restrict__ bo,
    const float* __restrict__ x, float* __restrict__ out)
{
    __shared__ float invZ[8];
    int tid = threadIdx.x;
    if (tid < 8) {
        float z = 0.f;
#pragma unroll
        for (int g = 0; g < 16; g++) z += Z2[g * 8 + tid];
        invZ[tid] = 1.0f / z;
    }
    __syncthreads();

    int wv   = tid >> 6;
    int l    = tid & 63;
    int rl   = l & 15;
    int kg   = l >> 4;
    int colh = blockIdx.x & 1;
    int row0 = (blockIdx.x >> 1) * 64 + wv * 16;

    bf16x8 a[4];
    const float* arow = agg + (size_t)(row0 + rl) * kHID + kg * 8;
#pragma unroll
    for (int kk = 0; kk < 4; kk++) {
        int head = (kk * 32 + kg * 8) >> 4;
        a[kk] = load_a8(arow + kk * 32, invZ[head]);
    }

    f32x4 acc[4];
#pragma unroll
    for (int t = 0; t < 4; t++) acc[t] = (f32x4){0.f, 0.f, 0.f, 0.f};
#pragma unroll
    for (int t = 0; t < 4; t++) {
        int c = (colh * 4 + t) * 16 + rl;
#pragma unroll
        for (int kk = 0; kk < 4; kk++) {
            bf16x8 b = *(const bf16x8*)(WTo + c * 128 + kk * 32 + kg * 8);
            acc[t] = __builtin_amdgcn_mfma_f32_16x16x32_bf16(a[kk], b, acc[t], 0, 0, 0);
        }
    }
#pragma unroll
    for (int t = 0; t < 4; t++) {
        int c = (colh * 4 + t) * 16 + rl;
        float bb = bo[c];
#pragma unroll
        for (int r = 0; r < 4; r++) {
            int node = row0 + kg * 4 + r;
            size_t off = (size_t)node * kHID + c;
            out[off] = x[off] + acc[t][r] + bb;
        }
    }
}

extern "C" void kernel_launch(void* const* d_in, const int* in_sizes, int n_in,
                              void* d_out, int out_size, void* d_ws, size_t ws_size,
                              hipStream_t stream) {
    const float* x     = (const float*)d_in[0];
    const int*   ei    = (const int*)d_in[1];
    // d_in[2] = edge_attr (unused by reference)
    const float* fv    = (const float*)d_in[3];
    const int*   batch = (const int*)d_in[4];
    const float* Wq = (const float*)d_in[5];  const float* bq = (const float*)d_in[6];
    const float* Wk = (const float*)d_in[7];  const float* bk = (const float*)d_in[8];
    const float* Wv = (const float*)d_in[9];  const float* bv = (const float*)d_in[10];
    const float* Wf = (const float*)d_in[11]; const float* bf = (const float*)d_in[12];
    const float* Wo = (const float*)d_in[13]; const float* bo = (const float*)d_in[14];

    float* ws     = (float*)d_ws;
    unsigned short* Qb = (unsigned short*)(ws + OFF_QB);
    float* agg    = ws + OFF_AGG;
    unsigned* KVw = (unsigned*)(ws + OFF_KV);
    float* FE     = ws + OFF_FE;
    float* Z2     = ws + OFF_Z2;
    unsigned short* WT = (unsigned short*)(ws + OFF_WT);
    int*   cnt    = (int*)(ws + OFF_CNT);
    int*   rowptr = (int*)(ws + OFF_ROWPTR);
    int*   cursor = (int*)(ws + OFF_CURSOR);
    int*   bsum   = (int*)(ws + OFF_BSUM);
    int*   dstc   = (int*)(ws + OFF_DSTC);
    float* out    = (float*)d_out;

    k_prep<<<105, 256, 0, stream>>>(Wq, Wk, Wv, Wo, fv, Wf, bf, WT, FE, Z2, cnt);

    // CSR build
    k_hist<<<kE / 256, 256, 0, stream>>>(ei, cnt);
    k_scan1<<<kNB, 256, 0, stream>>>(cnt, rowptr, bsum);
    k_scan23<<<kNB, 256, 0, stream>>>(bsum, rowptr, cursor);
    k_fill<<<kE / 256, 256, 0, stream>>>(ei, cursor, dstc);

    k_qkv<<<(kN / 64) * 2, 256, 0, stream>>>(x, batch, WT, bq, bk, bv, FE, Qb, KVw);

    k_edge<<<kN / 4, 256, 0, stream>>>(rowptr, dstc, Qb, KVw, agg, Z2);

    k_out<<<(kN / 64) * 2, 256, 0, stream>>>(agg, Z2, WT + 3 * 16384, bo, x, out);
}